// Round 4
// baseline (2607.103 us; speedup 1.0000x reference)
//
#include <hip/hip_runtime.h>
#include <hip/hip_bf16.h>
#include <math.h>

#define D 1024
#define NP 128
#define BS 2
#define GEO 64
#define TOPKN 18
#define NPAIR (BS*NP*NP)   // 32768

__device__ __forceinline__ float relu_(float x){ return fmaxf(x, 0.f); }

// ---------------- geo embedding + 3x Linear(64,64) MLP (chunk-local) ----------
// one wave per pair; lane c owns channel c; gp weights staged in LDS.
// computes pairs [pofs, pofs + gridDim.x*4), writes chunk-local geoPc.
__global__ __launch_bounds__(256) void k_geo(
    const float* __restrict__ prop,
    const float* __restrict__ gw1, const float* __restrict__ gb1,
    const float* __restrict__ gw2, const float* __restrict__ gb2,
    const float* __restrict__ gw3, const float* __restrict__ gb3,
    float* __restrict__ geoPc, int pofs)
{
    __shared__ float w[3][GEO*GEO];
    __shared__ float bias[3][GEO];
    int tid = threadIdx.x;
    for (int idx = tid; idx < GEO*GEO; idx += 256) {
        w[0][idx] = gw1[idx]; w[1][idx] = gw2[idx]; w[2][idx] = gw3[idx];
    }
    if (tid < GEO) { bias[0][tid]=gb1[tid]; bias[1][tid]=gb2[tid]; bias[2][tid]=gb3[tid]; }
    __syncthreads();
    int lane = tid & 63;
    int wave = tid >> 6;
    int gwave = blockIdx.x*4 + wave;     // chunk-local pair index
    int pair  = pofs + gwave;            // global pair index
    // channel c = p*16 + s ; s<8 -> sin(div[p][s]), s>=8 -> cos(div[p][s-8])
    int p = lane >> 4;
    int s = lane & 15;
    int f = s & 7;
    float dm = expf((float)f * (6.907755278982137f/8.0f)); // 1000^(f/8)
    bool is_cos = (s & 8) != 0;
    float scale = 100.f / dm;

    int b  = pair >> 14;
    int ij = pair & 16383;
    int i  = ij >> 7;
    int j  = ij & 127;
    float4 pi = *(const float4*)(prop + (size_t)(b*NP + i)*4);
    float4 pj = *(const float4*)(prop + (size_t)(b*NP + j)*4);
    float xi0=pi.x, yi0=pi.y, xi1=pi.z, yi1=pi.w;
    float xj0=pj.x, yj0=pj.y, xj1=pj.z, yj1=pj.w;
    float wi  = xi1-xi0+1.f, hi_ = yi1-yi0+1.f;
    float wj  = xj1-xj0+1.f, hj  = yj1-yj0+1.f;
    float pos;
    if      (p == 0) pos = (0.5f*(xi0+xi1) - 0.5f*(xj0+xj1)) / wj;  // dx[i,j]
    else if (p == 1) pos = (0.5f*(yi0+yi1) - 0.5f*(yj0+yj1)) / hj;  // dy[i,j]
    else if (p == 2) pos = wi / wj;                                  // dw
    else             pos = hi_ / hj;                                 // dh
    pos = logf(fmaxf(fabsf(pos), 1e-3f));
    float dv = pos * scale;
    float v = is_cos ? cosf(dv) : sinf(dv);
    #pragma unroll
    for (int layer = 0; layer < 3; ++layer) {
        float acc = bias[layer][lane];
        for (int k = 0; k < GEO; ++k) {
            float vk = __shfl(v, k, 64);
            acc = fmaf(vk, w[layer][k*GEO + lane], acc);
        }
        v = (layer < 2) ? relu_(acc) : acc;
    }
    geoPc[(size_t)gwave*GEO + lane] = v;
}

// ---------------- generic GEMM: C[M,N] = act((ACCUM?C:0) + A[M,K]@W[K,N] + bias) ---
// all f32. 64x64 tile, BK=16, 256 threads, 4x4 per thread. M%64==0, N%64==0, K%16==0.
template<bool RELU, bool ACCUM>
__global__ __launch_bounds__(256) void k_gemm(
    const float* __restrict__ A, int lda,
    const float* __restrict__ W, int ldw,
    const float* __restrict__ bias,
    float* __restrict__ C, int ldc,
    int K)
{
    __shared__ float As[16][64];
    __shared__ float Bs[16][64];
    int tid = threadIdx.x;
    int m0 = blockIdx.x * 64;
    int n0 = blockIdx.y * 64;
    int tx = tid & 15, ty = tid >> 4;
    int ar = tid >> 2, ac = (tid & 3) * 4;   // A tile load: row ar, k-offset ac
    int br = tid >> 4, bc = (tid & 15) * 4;  // B tile load: k-row br, n-offset bc
    float acc[4][4] = {};
    const float* Aptr = A + (size_t)(m0 + ar)*lda + ac;
    const float* Wptr = W + (size_t)br*ldw + n0 + bc;
    for (int k0 = 0; k0 < K; k0 += 16) {
        float4 a4 = *(const float4*)(Aptr + k0);
        float4 b4 = *(const float4*)(Wptr + (size_t)k0*ldw);
        __syncthreads();
        As[ac+0][ar] = a4.x; As[ac+1][ar] = a4.y; As[ac+2][ar] = a4.z; As[ac+3][ar] = a4.w;
        *(float4*)&Bs[br][bc] = b4;
        __syncthreads();
        #pragma unroll
        for (int k = 0; k < 16; ++k) {
            float4 av = *(const float4*)&As[k][ty*4];
            float4 bv = *(const float4*)&Bs[k][tx*4];
            float a_[4] = {av.x, av.y, av.z, av.w};
            float b_[4] = {bv.x, bv.y, bv.z, bv.w};
            #pragma unroll
            for (int mi = 0; mi < 4; ++mi)
                #pragma unroll
                for (int ni = 0; ni < 4; ++ni)
                    acc[mi][ni] = fmaf(a_[mi], b_[ni], acc[mi][ni]);
        }
    }
    float4 bv4 = make_float4(0.f, 0.f, 0.f, 0.f);
    if (bias) bv4 = *(const float4*)(bias + n0 + tx*4);
    #pragma unroll
    for (int mi = 0; mi < 4; ++mi) {
        int m = m0 + ty*4 + mi;
        float* cp = C + (size_t)m*ldc + n0 + tx*4;
        float4 o;
        o.x = acc[mi][0] + bv4.x; o.y = acc[mi][1] + bv4.y;
        o.z = acc[mi][2] + bv4.z; o.w = acc[mi][3] + bv4.w;
        if (ACCUM) {
            float4 c0 = *(const float4*)cp;
            o.x += c0.x; o.y += c0.y; o.z += c0.z; o.w += c0.w;
        }
        if (RELU) { o.x=relu_(o.x); o.y=relu_(o.y); o.z=relu_(o.z); o.w=relu_(o.w); }
        *(float4*)cp = o;
    }
}

// ---------------- h1 = relu(U[b,j] + V[b,i] + geoPc[.]@W1c + b1) ----------------
// 8 consecutive pairs per block (same b,i; j0..j0+7); thread owns 4 channels.
__global__ __launch_bounds__(256) void k_h1(
    const float* __restrict__ geoPc, const float* __restrict__ W1c,
    const float* __restrict__ b1,
    const float* __restrict__ U, const float* __restrict__ V,
    float* __restrict__ h1c, int pofs)
{
    __shared__ float g[8][GEO];
    int pl    = blockIdx.x * 8;       // chunk-local pair base
    int pbase = pofs + pl;            // global pair base
    int b  = pbase >> 14;
    int ij = pbase & 16383;
    int i  = ij >> 7;
    int j0 = ij & 127;
    int tid = threadIdx.x;
    for (int t = tid; t < 8*GEO; t += 256) ((float*)g)[t] = geoPc[(size_t)pl*GEO + t];
    __syncthreads();
    int c = tid * 4;
    float4 base4 = *(const float4*)(b1 + c);
    float4 vv = *(const float4*)(V + (size_t)(b*NP + i)*D + c);
    base4.x += vv.x; base4.y += vv.y; base4.z += vv.z; base4.w += vv.w;
    float4 acc[8];
    #pragma unroll
    for (int pp = 0; pp < 8; ++pp) {
        float4 uu = *(const float4*)(U + (size_t)(b*NP + j0 + pp)*D + c);
        acc[pp].x = base4.x + uu.x; acc[pp].y = base4.y + uu.y;
        acc[pp].z = base4.z + uu.z; acc[pp].w = base4.w + uu.w;
    }
    for (int k = 0; k < GEO; ++k) {
        float4 w4 = *(const float4*)(W1c + (size_t)k*D + c);
        #pragma unroll
        for (int pp = 0; pp < 8; ++pp) {
            float gk = g[pp][k];
            acc[pp].x = fmaf(gk, w4.x, acc[pp].x);
            acc[pp].y = fmaf(gk, w4.y, acc[pp].y);
            acc[pp].z = fmaf(gk, w4.z, acc[pp].z);
            acc[pp].w = fmaf(gk, w4.w, acc[pp].w);
        }
    }
    #pragma unroll
    for (int pp = 0; pp < 8; ++pp) {
        float4 o = acc[pp];
        o.x=relu_(o.x); o.y=relu_(o.y); o.z=relu_(o.z); o.w=relu_(o.w);
        *(float4*)(h1c + (size_t)(pl + pp)*D + c) = o;
    }
}

// ---------------- top-18 over j, sum/8 (per chunk of CH rows) ----------------
// one thread per (bi_local, c); register-only unrolled bubble-insert (18 deep).
__global__ __launch_bounds__(256) void k_topk(const float* __restrict__ fc,
                                              float* __restrict__ red_out)
{
    int gid = blockIdx.x*256 + threadIdx.x;      // = bi_local*D + c
    int c  = gid & (D-1);
    int bl = gid >> 10;
    const float* base = fc + (size_t)bl*NP*D + c;
    float sm[TOPKN];
    #pragma unroll
    for (int t = 0; t < TOPKN; ++t) sm[t] = -INFINITY;
    for (int j = 0; j < NP; ++j) {
        float v = base[(size_t)j*D];
        #pragma unroll
        for (int t = 0; t < TOPKN; ++t) {
            float mx = fmaxf(sm[t], v);
            v = fminf(sm[t], v);
            sm[t] = mx;
        }
    }
    float ssum = 0.f;
    #pragma unroll
    for (int t = 0; t < TOPKN; ++t) ssum += sm[t];
    red_out[gid] = ssum * 0.125f;
}

// ---------------- final heads -> sigmoid, f32 out ----------------
__global__ __launch_bounds__(256) void k_final(const float* __restrict__ x,
    const float* __restrict__ subject, const float* __restrict__ obj,
    const float* __restrict__ cs_w, const float* __restrict__ cs_b,
    const float* __restrict__ cso_w, const float* __restrict__ cso_b,
    float* __restrict__ out)
{
    int bi = blockIdx.x;
    int b  = bi >> 7;
    const float* xr = x + (size_t)bi*D;
    const float* sb = subject + (size_t)b*D;
    const float* ob = obj + (size_t)b*D;
    int tid = threadIdx.x;
    float a0 = 0.f, a1 = 0.f;
    for (int k = tid; k < D; k += 256) {
        float xv = xr[k];
        a0 = fmaf(xv, cs_w[k], a0);
        a0 = fmaf(sb[k], cs_w[D+k], a0);
        a1 = fmaf(xv, cso_w[k], a1);
        a1 = fmaf(ob[k], cso_w[D+k], a1);
    }
    __shared__ float r0[256], r1[256];
    r0[tid] = a0; r1[tid] = a1;
    __syncthreads();
    for (int s2 = 128; s2 > 0; s2 >>= 1) {
        if (tid < s2) { r0[tid] += r0[tid+s2]; r1[tid] += r1[tid+s2]; }
        __syncthreads();
    }
    if (tid == 0) {
        out[bi*2+0] = 1.f/(1.f + expf(-(r0[0] + cs_b[0])));
        out[bi*2+1] = 1.f/(1.f + expf(-(r1[0] + cso_b[0])));
    }
}

extern "C" void kernel_launch(void* const* d_in, const int* in_sizes, int n_in,
                              void* d_out, int out_size, void* d_ws, size_t ws_size,
                              hipStream_t stream)
{
    const float* feats   = (const float*)d_in[0];
    const float* subject = (const float*)d_in[1];
    const float* obj     = (const float*)d_in[2];
    const float* prop    = (const float*)d_in[3];
    const float* gp_w1 = (const float*)d_in[4];  const float* gp_b1 = (const float*)d_in[5];
    const float* gp_w2 = (const float*)d_in[6];  const float* gp_b2 = (const float*)d_in[7];
    const float* gp_w3 = (const float*)d_in[8];  const float* gp_b3 = (const float*)d_in[9];
    const float* pm_w1 = (const float*)d_in[10]; const float* pm_b1 = (const float*)d_in[11];
    const float* pm_w2 = (const float*)d_in[12]; const float* pm_b2 = (const float*)d_in[13];
    const float* pm_w3 = (const float*)d_in[14]; const float* pm_b3 = (const float*)d_in[15];
    const float* ag_w1 = (const float*)d_in[16]; const float* ag_b1 = (const float*)d_in[17];
    const float* ag_w2 = (const float*)d_in[18]; const float* ag_b2 = (const float*)d_in[19];
    const float* ag_w3 = (const float*)d_in[20]; const float* ag_b3 = (const float*)d_in[21];
    const float* cs_w  = (const float*)d_in[22]; const float* cs_b  = (const float*)d_in[23];
    const float* cso_w = (const float*)d_in[24]; const float* cso_b = (const float*)d_in[25];
    float* out = (float*)d_out;

    // ---- workspace layout (floats). Persistent: 6 * 256K floats = 6.3 MB. ----
    float* ws = (float*)d_ws;
    size_t off = 0;
    float* Ub  = ws + off; off += (size_t)BS*NP*D;
    float* Vb  = ws + off; off += (size_t)BS*NP*D;
    float* red = ws + off; off += (size_t)BS*NP*D;
    float* xh1 = ws + off; off += (size_t)BS*NP*D;
    float* xh2 = ws + off; off += (size_t)BS*NP*D;
    float* xf  = ws + off; off += (size_t)BS*NP*D;
    size_t persist = off;

    // chunk size CH (rows of i per pass): needs CH*NP*(GEO + 3*D) extra floats.
    // deterministic in ws_size -> graph-capture safe.
    int CH = 64;
    while (CH > 1 && (persist + (size_t)CH*NP*(GEO + 3*D))*4ull > ws_size) CH >>= 1;
    float* geoPc = ws + persist;
    float* h1c = geoPc + (size_t)CH*NP*GEO;
    float* h2c = h1c + (size_t)CH*NP*D;
    float* fc  = h2c + (size_t)CH*NP*D;

    const float* W1c = pm_w1 + (size_t)2*D*D;   // geo part of pm_w1

    // 1) U = feats @ pm_w1[0:1024,:]   (x1 = feats[b,j] part)
    //    V = feats @ pm_w1[1024:2048,:](x2 = feats[b,i] part)
    dim3 gUV(BS*NP/64, D/64);
    k_gemm<false,false><<<gUV, 256, 0, stream>>>(feats, D, pm_w1,               D, nullptr, Ub, D, D);
    k_gemm<false,false><<<gUV, 256, 0, stream>>>(feats, D, pm_w1 + (size_t)D*D, D, nullptr, Vb, D, D);

    // 2) chunked over (b,i) rows: geo -> h1 -> h2 -> fet -> topk
    int nchunks = (BS*NP)/CH;
    for (int cchunk = 0; cchunk < nchunks; ++cchunk) {
        int bi0  = cchunk * CH;
        int pofs = bi0 * NP;
        k_geo<<<CH*NP/4, 256, 0, stream>>>(prop, gp_w1, gp_b1, gp_w2, gp_b2, gp_w3, gp_b3, geoPc, pofs);
        k_h1<<<CH*NP/8, 256, 0, stream>>>(geoPc, W1c, pm_b1, Ub, Vb, h1c, pofs);
        dim3 gBig(CH*NP/64, D/64);
        k_gemm<true ,false><<<gBig, 256, 0, stream>>>(h1c, D, pm_w2, D, pm_b2, h2c, D, D);
        k_gemm<false,false><<<gBig, 256, 0, stream>>>(h2c, D, pm_w3, D, pm_b3, fc,  D, D);
        k_topk<<<CH*D/256, 256, 0, stream>>>(fc, red + (size_t)bi0*D);
    }

    // 3) aggregate MLP: layer1 split as feats@W1a + red@W1b + b (accumulate)
    k_gemm<false,false><<<gUV, 256, 0, stream>>>(feats, D, ag_w1,               D, nullptr, xh1, D, D);
    k_gemm<true ,true ><<<gUV, 256, 0, stream>>>(red,   D, ag_w1 + (size_t)D*D, D, ag_b1,  xh1, D, D);
    k_gemm<true ,false><<<gUV, 256, 0, stream>>>(xh1,   D, ag_w2, D, ag_b2, xh2, D, D);
    k_gemm<false,false><<<gUV, 256, 0, stream>>>(xh2,   D, ag_w3, D, ag_b3, xf,  D, D);

    // 4) sigmoid heads
    k_final<<<BS*NP, 256, 0, stream>>>(xf, subject, obj, cs_w, cs_b, cso_w, cso_b, out);
}

// Round 5
// 1119.269 us; speedup vs baseline: 2.3293x; 2.3293x over previous
//
#include <hip/hip_runtime.h>
#include <hip/hip_bf16.h>
#include <math.h>

#define D 1024
#define NP 128
#define BS 2
#define GEO 64
#define TOPKN 18
#define NPAIR (BS*NP*NP)   // 32768

__device__ __forceinline__ float relu_(float x){ return fmaxf(x, 0.f); }
__device__ __forceinline__ unsigned short f2b(float x){
    __hip_bfloat16 h = __float2bfloat16(x);
    return *(unsigned short*)&h;
}

typedef short bf16x8 __attribute__((ext_vector_type(8)));
typedef float f32x4  __attribute__((ext_vector_type(4)));

// ---------------- geo embedding + 3x Linear(64,64) MLP (chunk-local) ----------
__global__ __launch_bounds__(256) void k_geo(
    const float* __restrict__ prop,
    const float* __restrict__ gw1, const float* __restrict__ gb1,
    const float* __restrict__ gw2, const float* __restrict__ gb2,
    const float* __restrict__ gw3, const float* __restrict__ gb3,
    float* __restrict__ geoPc, int pofs)
{
    __shared__ float w[3][GEO*GEO];
    __shared__ float bias[3][GEO];
    int tid = threadIdx.x;
    for (int idx = tid; idx < GEO*GEO; idx += 256) {
        w[0][idx] = gw1[idx]; w[1][idx] = gw2[idx]; w[2][idx] = gw3[idx];
    }
    if (tid < GEO) { bias[0][tid]=gb1[tid]; bias[1][tid]=gb2[tid]; bias[2][tid]=gb3[tid]; }
    __syncthreads();
    int lane = tid & 63;
    int wave = tid >> 6;
    int gwave = blockIdx.x*4 + wave;     // chunk-local pair index
    int pair  = pofs + gwave;            // global pair index
    int p = lane >> 4;
    int s = lane & 15;
    int f = s & 7;
    float dm = expf((float)f * (6.907755278982137f/8.0f)); // 1000^(f/8)
    bool is_cos = (s & 8) != 0;
    float scale = 100.f / dm;

    int b  = pair >> 14;
    int ij = pair & 16383;
    int i  = ij >> 7;
    int j  = ij & 127;
    float4 pi = *(const float4*)(prop + (size_t)(b*NP + i)*4);
    float4 pj = *(const float4*)(prop + (size_t)(b*NP + j)*4);
    float wi  = pi.z-pi.x+1.f, hi_ = pi.w-pi.y+1.f;
    float wj  = pj.z-pj.x+1.f, hj  = pj.w-pj.y+1.f;
    float pos;
    if      (p == 0) pos = (0.5f*(pi.x+pi.z) - 0.5f*(pj.x+pj.z)) / wj;
    else if (p == 1) pos = (0.5f*(pi.y+pi.w) - 0.5f*(pj.y+pj.w)) / hj;
    else if (p == 2) pos = wi / wj;
    else             pos = hi_ / hj;
    pos = logf(fmaxf(fabsf(pos), 1e-3f));
    float dv = pos * scale;
    float v = is_cos ? cosf(dv) : sinf(dv);
    #pragma unroll
    for (int layer = 0; layer < 3; ++layer) {
        float acc = bias[layer][lane];
        for (int k = 0; k < GEO; ++k) {
            float vk = __shfl(v, k, 64);
            acc = fmaf(vk, w[layer][k*GEO + lane], acc);
        }
        v = (layer < 2) ? relu_(acc) : acc;
    }
    geoPc[(size_t)gwave*GEO + lane] = v;
}

// ---------------- f32 GEMM (small matrices): C = act((ACCUM?C:0)+A@W+bias) -----
template<bool RELU, bool ACCUM>
__global__ __launch_bounds__(256) void k_gemm(
    const float* __restrict__ A, int lda,
    const float* __restrict__ W, int ldw,
    const float* __restrict__ bias,
    float* __restrict__ C, int ldc,
    int K)
{
    __shared__ float As[16][64];
    __shared__ float Bs[16][64];
    int tid = threadIdx.x;
    int m0 = blockIdx.x * 64;
    int n0 = blockIdx.y * 64;
    int tx = tid & 15, ty = tid >> 4;
    int ar = tid >> 2, ac = (tid & 3) * 4;
    int br = tid >> 4, bc = (tid & 15) * 4;
    float acc[4][4] = {};
    const float* Aptr = A + (size_t)(m0 + ar)*lda + ac;
    const float* Wptr = W + (size_t)br*ldw + n0 + bc;
    for (int k0 = 0; k0 < K; k0 += 16) {
        float4 a4 = *(const float4*)(Aptr + k0);
        float4 b4 = *(const float4*)(Wptr + (size_t)k0*ldw);
        __syncthreads();
        As[ac+0][ar] = a4.x; As[ac+1][ar] = a4.y; As[ac+2][ar] = a4.z; As[ac+3][ar] = a4.w;
        *(float4*)&Bs[br][bc] = b4;
        __syncthreads();
        #pragma unroll
        for (int k = 0; k < 16; ++k) {
            float4 av = *(const float4*)&As[k][ty*4];
            float4 bv = *(const float4*)&Bs[k][tx*4];
            float a_[4] = {av.x, av.y, av.z, av.w};
            float b_[4] = {bv.x, bv.y, bv.z, bv.w};
            #pragma unroll
            for (int mi = 0; mi < 4; ++mi)
                #pragma unroll
                for (int ni = 0; ni < 4; ++ni)
                    acc[mi][ni] = fmaf(a_[mi], b_[ni], acc[mi][ni]);
        }
    }
    float4 bv4 = make_float4(0.f, 0.f, 0.f, 0.f);
    if (bias) bv4 = *(const float4*)(bias + n0 + tx*4);
    #pragma unroll
    for (int mi = 0; mi < 4; ++mi) {
        int m = m0 + ty*4 + mi;
        float* cp = C + (size_t)m*ldc + n0 + tx*4;
        float4 o;
        o.x = acc[mi][0] + bv4.x; o.y = acc[mi][1] + bv4.y;
        o.z = acc[mi][2] + bv4.z; o.w = acc[mi][3] + bv4.w;
        if (ACCUM) {
            float4 c0 = *(const float4*)cp;
            o.x += c0.x; o.y += c0.y; o.z += c0.z; o.w += c0.w;
        }
        if (RELU) { o.x=relu_(o.x); o.y=relu_(o.y); o.z=relu_(o.z); o.w=relu_(o.w); }
        *(float4*)cp = o;
    }
}

// ---------------- transpose + f32->bf16: WT[n][k] = bf16(W[k][n]) ----------------
__global__ __launch_bounds__(256) void k_wT(const float* __restrict__ W,
                                            unsigned short* __restrict__ WT,
                                            int K, int N)
{
    __shared__ float tile[64][65];
    int bx = blockIdx.x;  // along N
    int by = blockIdx.y;  // along K
    int t = threadIdx.x;
    int tc = t & 63, tr = t >> 6;
    #pragma unroll
    for (int r = tr; r < 64; r += 4)
        tile[r][tc] = W[(size_t)(by*64 + r)*N + bx*64 + tc];
    __syncthreads();
    #pragma unroll
    for (int r = tr; r < 64; r += 4)
        WT[(size_t)(bx*64 + r)*K + by*64 + tc] = f2b(tile[tc][r]);
}

// ---------------- bf16 MFMA GEMM: C[M,N] = act(A@B + bias) ----------------
// A [M,K] bf16 row-major; BT [N,K] bf16 row-major (i.e. B transposed).
// 128x128 block tile, 4 waves (2x2), each wave 64x64 via 4x4 of 16x16x32 MFMA.
#define LDST 40   // LDS row stride in bf16 (16B-aligned, bank-spread)
template<bool RELU, bool OUT_BF16>
__global__ __launch_bounds__(256) void k_mgemm(
    const unsigned short* __restrict__ A,
    const unsigned short* __restrict__ BT,
    const float* __restrict__ bias,
    void* __restrict__ Cv, int M, int N, int K)
{
    __shared__ unsigned short As[128*LDST];
    __shared__ unsigned short Bs[128*LDST];
    int t  = threadIdx.x;
    int m0 = blockIdx.x * 128;
    int n0 = blockIdx.y * 128;
    int w  = t >> 6, l = t & 63;
    int wm = w & 1, wn = w >> 1;
    int lr = l & 15;      // row-in-16 (A) / col-in-16 (B)
    int lq = l >> 4;      // quad -> k-offset lq*8

    // staging chunk ids: c0 covers rows 0..63, c1 rows 64..127 (4 chunks/row)
    int c0 = t, c1 = t + 256;
    int r0 = c0 >> 2, ko0 = (c0 & 3) * 8;
    int r1 = c1 >> 2, ko1 = (c1 & 3) * 8;

    f32x4 acc[4][4];
    #pragma unroll
    for (int mi = 0; mi < 4; ++mi)
        #pragma unroll
        for (int ni = 0; ni < 4; ++ni)
            #pragma unroll
            for (int r = 0; r < 4; ++r) acc[mi][ni][r] = 0.f;

    for (int k0 = 0; k0 < K; k0 += 32) {
        __syncthreads();
        *(bf16x8*)(As + r0*LDST + ko0) = *(const bf16x8*)(A  + (size_t)(m0 + r0)*K + k0 + ko0);
        *(bf16x8*)(As + r1*LDST + ko1) = *(const bf16x8*)(A  + (size_t)(m0 + r1)*K + k0 + ko1);
        *(bf16x8*)(Bs + r0*LDST + ko0) = *(const bf16x8*)(BT + (size_t)(n0 + r0)*K + k0 + ko0);
        *(bf16x8*)(Bs + r1*LDST + ko1) = *(const bf16x8*)(BT + (size_t)(n0 + r1)*K + k0 + ko1);
        __syncthreads();
        bf16x8 af[4], bf[4];
        #pragma unroll
        for (int mi = 0; mi < 4; ++mi)
            af[mi] = *(const bf16x8*)(As + (wm*64 + mi*16 + lr)*LDST + lq*8);
        #pragma unroll
        for (int ni = 0; ni < 4; ++ni)
            bf[ni] = *(const bf16x8*)(Bs + (wn*64 + ni*16 + lr)*LDST + lq*8);
        #pragma unroll
        for (int mi = 0; mi < 4; ++mi)
            #pragma unroll
            for (int ni = 0; ni < 4; ++ni)
                acc[mi][ni] = __builtin_amdgcn_mfma_f32_16x16x32_bf16(af[mi], bf[ni], acc[mi][ni], 0, 0, 0);
    }

    // epilogue: D[row=(lq*4+r)][col=lr] per 16x16 tile
    #pragma unroll
    for (int mi = 0; mi < 4; ++mi) {
        #pragma unroll
        for (int ni = 0; ni < 4; ++ni) {
            int gc = n0 + wn*64 + ni*16 + lr;
            int gr = m0 + wm*64 + mi*16 + lq*4;
            float bval = bias ? bias[gc] : 0.f;
            #pragma unroll
            for (int r = 0; r < 4; ++r) {
                float v = acc[mi][ni][r] + bval;
                if (RELU) v = relu_(v);
                if (OUT_BF16) ((unsigned short*)Cv)[(size_t)(gr + r)*N + gc] = f2b(v);
                else          ((float*)Cv)[(size_t)(gr + r)*N + gc] = v;
            }
        }
    }
}

// ---------------- h1 = relu(U[b,j] + V[b,i] + geoPc@W1c + b1) -> bf16 ----------
__global__ __launch_bounds__(256) void k_h1(
    const float* __restrict__ geoPc, const float* __restrict__ W1c,
    const float* __restrict__ b1,
    const float* __restrict__ U, const float* __restrict__ V,
    unsigned short* __restrict__ h1c, int pofs)
{
    __shared__ float g[8][GEO];
    int pl    = blockIdx.x * 8;
    int pbase = pofs + pl;
    int b  = pbase >> 14;
    int ij = pbase & 16383;
    int i  = ij >> 7;
    int j0 = ij & 127;
    int tid = threadIdx.x;
    for (int t = tid; t < 8*GEO; t += 256) ((float*)g)[t] = geoPc[(size_t)pl*GEO + t];
    __syncthreads();
    int c = tid * 4;
    float4 base4 = *(const float4*)(b1 + c);
    float4 vv = *(const float4*)(V + (size_t)(b*NP + i)*D + c);
    base4.x += vv.x; base4.y += vv.y; base4.z += vv.z; base4.w += vv.w;
    float4 acc[8];
    #pragma unroll
    for (int pp = 0; pp < 8; ++pp) {
        float4 uu = *(const float4*)(U + (size_t)(b*NP + j0 + pp)*D + c);
        acc[pp].x = base4.x + uu.x; acc[pp].y = base4.y + uu.y;
        acc[pp].z = base4.z + uu.z; acc[pp].w = base4.w + uu.w;
    }
    for (int k = 0; k < GEO; ++k) {
        float4 w4 = *(const float4*)(W1c + (size_t)k*D + c);
        #pragma unroll
        for (int pp = 0; pp < 8; ++pp) {
            float gk = g[pp][k];
            acc[pp].x = fmaf(gk, w4.x, acc[pp].x);
            acc[pp].y = fmaf(gk, w4.y, acc[pp].y);
            acc[pp].z = fmaf(gk, w4.z, acc[pp].z);
            acc[pp].w = fmaf(gk, w4.w, acc[pp].w);
        }
    }
    #pragma unroll
    for (int pp = 0; pp < 8; ++pp) {
        ushort4 o;
        o.x = f2b(relu_(acc[pp].x)); o.y = f2b(relu_(acc[pp].y));
        o.z = f2b(relu_(acc[pp].z)); o.w = f2b(relu_(acc[pp].w));
        *(ushort4*)(h1c + (size_t)(pl + pp)*D + c) = o;
    }
}

// ---------------- top-18 over j, sum/8 (per chunk of CH rows) ----------------
__global__ __launch_bounds__(256) void k_topk(const float* __restrict__ fc,
                                              float* __restrict__ red_out)
{
    int gid = blockIdx.x*256 + threadIdx.x;
    int c  = gid & (D-1);
    int bl = gid >> 10;
    const float* base = fc + (size_t)bl*NP*D + c;
    float sm[TOPKN];
    #pragma unroll
    for (int t = 0; t < TOPKN; ++t) sm[t] = -INFINITY;
    for (int j = 0; j < NP; ++j) {
        float v = base[(size_t)j*D];
        #pragma unroll
        for (int t = 0; t < TOPKN; ++t) {
            float mx = fmaxf(sm[t], v);
            v = fminf(sm[t], v);
            sm[t] = mx;
        }
    }
    float ssum = 0.f;
    #pragma unroll
    for (int t = 0; t < TOPKN; ++t) ssum += sm[t];
    red_out[gid] = ssum * 0.125f;
}

// ---------------- final heads -> sigmoid, f32 out ----------------
__global__ __launch_bounds__(256) void k_final(const float* __restrict__ x,
    const float* __restrict__ subject, const float* __restrict__ obj,
    const float* __restrict__ cs_w, const float* __restrict__ cs_b,
    const float* __restrict__ cso_w, const float* __restrict__ cso_b,
    float* __restrict__ out)
{
    int bi = blockIdx.x;
    int b  = bi >> 7;
    const float* xr = x + (size_t)bi*D;
    const float* sb = subject + (size_t)b*D;
    const float* ob = obj + (size_t)b*D;
    int tid = threadIdx.x;
    float a0 = 0.f, a1 = 0.f;
    for (int k = tid; k < D; k += 256) {
        float xv = xr[k];
        a0 = fmaf(xv, cs_w[k], a0);
        a0 = fmaf(sb[k], cs_w[D+k], a0);
        a1 = fmaf(xv, cso_w[k], a1);
        a1 = fmaf(ob[k], cso_w[D+k], a1);
    }
    __shared__ float r0[256], r1[256];
    r0[tid] = a0; r1[tid] = a1;
    __syncthreads();
    for (int s2 = 128; s2 > 0; s2 >>= 1) {
        if (tid < s2) { r0[tid] += r0[tid+s2]; r1[tid] += r1[tid+s2]; }
        __syncthreads();
    }
    if (tid == 0) {
        out[bi*2+0] = 1.f/(1.f + expf(-(r0[0] + cs_b[0])));
        out[bi*2+1] = 1.f/(1.f + expf(-(r1[0] + cso_b[0])));
    }
}

extern "C" void kernel_launch(void* const* d_in, const int* in_sizes, int n_in,
                              void* d_out, int out_size, void* d_ws, size_t ws_size,
                              hipStream_t stream)
{
    const float* feats   = (const float*)d_in[0];
    const float* subject = (const float*)d_in[1];
    const float* obj     = (const float*)d_in[2];
    const float* prop    = (const float*)d_in[3];
    const float* gp_w1 = (const float*)d_in[4];  const float* gp_b1 = (const float*)d_in[5];
    const float* gp_w2 = (const float*)d_in[6];  const float* gp_b2 = (const float*)d_in[7];
    const float* gp_w3 = (const float*)d_in[8];  const float* gp_b3 = (const float*)d_in[9];
    const float* pm_w1 = (const float*)d_in[10]; const float* pm_b1 = (const float*)d_in[11];
    const float* pm_w2 = (const float*)d_in[12]; const float* pm_b2 = (const float*)d_in[13];
    const float* pm_w3 = (const float*)d_in[14]; const float* pm_b3 = (const float*)d_in[15];
    const float* ag_w1 = (const float*)d_in[16]; const float* ag_b1 = (const float*)d_in[17];
    const float* ag_w2 = (const float*)d_in[18]; const float* ag_b2 = (const float*)d_in[19];
    const float* ag_w3 = (const float*)d_in[20]; const float* ag_b3 = (const float*)d_in[21];
    const float* cs_w  = (const float*)d_in[22]; const float* cs_b  = (const float*)d_in[23];
    const float* cso_w = (const float*)d_in[24]; const float* cso_b = (const float*)d_in[25];
    float* out = (float*)d_out;

    // ---- workspace layout (bytes) ----
    char* wsb = (char*)d_ws;
    size_t off = 0;
    auto alloc = [&](size_t bytes) { char* p = wsb + off; off += (bytes + 255) & ~255ull; return p; };
    float* Ub  = (float*)alloc((size_t)BS*NP*D*4);
    float* Vb  = (float*)alloc((size_t)BS*NP*D*4);
    float* red = (float*)alloc((size_t)BS*NP*D*4);
    float* xh1 = (float*)alloc((size_t)BS*NP*D*4);
    float* xh2 = (float*)alloc((size_t)BS*NP*D*4);
    float* xf  = (float*)alloc((size_t)BS*NP*D*4);
    unsigned short* w2T = (unsigned short*)alloc((size_t)D*D*2);
    unsigned short* w3T = (unsigned short*)alloc((size_t)D*D*2);
    size_t persist = off;

    // chunk: geoPc f32 + h1c bf16 + h2c bf16 + fc f32  = CH*128*(64*4+1024*2+1024*2+1024*4) B
    size_t chunk_unit = (size_t)NP*(GEO*4 + D*2 + D*2 + D*4);
    int CH = 64;
    while (CH > 1 && persist + (size_t)CH*chunk_unit + 4096 > ws_size) CH >>= 1;
    float*          geoPc = (float*)(wsb + persist);
    unsigned short* h1c   = (unsigned short*)((char*)geoPc + (size_t)CH*NP*GEO*4);
    unsigned short* h2c   = (unsigned short*)((char*)h1c   + (size_t)CH*NP*D*2);
    float*          fc    = (float*)((char*)h2c            + (size_t)CH*NP*D*2);

    const float* W1c = pm_w1 + (size_t)2*D*D;   // geo slice of pm_w1

    // 0) weights -> bf16 transposed
    dim3 gT(D/64, D/64);
    k_wT<<<gT, 256, 0, stream>>>(pm_w2, w2T, D, D);
    k_wT<<<gT, 256, 0, stream>>>(pm_w3, w3T, D, D);

    // 1) U = feats @ pm_w1[0:1024,:] ; V = feats @ pm_w1[1024:2048,:]
    dim3 gUV(BS*NP/64, D/64);
    k_gemm<false,false><<<gUV, 256, 0, stream>>>(feats, D, pm_w1,               D, nullptr, Ub, D, D);
    k_gemm<false,false><<<gUV, 256, 0, stream>>>(feats, D, pm_w1 + (size_t)D*D, D, nullptr, Vb, D, D);

    // 2) chunked over (b,i) rows: geo -> h1(bf16) -> h2(bf16,MFMA) -> fet(f32,MFMA) -> topk
    int nchunks = (BS*NP)/CH;
    for (int cchunk = 0; cchunk < nchunks; ++cchunk) {
        int bi0  = cchunk * CH;
        int pofs = bi0 * NP;
        k_geo<<<CH*NP/4, 256, 0, stream>>>(prop, gp_w1, gp_b1, gp_w2, gp_b2, gp_w3, gp_b3, geoPc, pofs);
        k_h1<<<CH*NP/8, 256, 0, stream>>>(geoPc, W1c, pm_b1, Ub, Vb, h1c, pofs);
        dim3 gBig(CH*NP/128, D/128);
        k_mgemm<true ,true ><<<gBig, 256, 0, stream>>>(h1c, w2T, pm_b2, h2c, CH*NP, D, D);
        k_mgemm<false,false><<<gBig, 256, 0, stream>>>(h2c, w3T, pm_b3, fc,  CH*NP, D, D);
        k_topk<<<CH*D/256, 256, 0, stream>>>(fc, red + (size_t)bi0*D);
    }

    // 3) aggregate MLP: layer1 split as feats@W1a + red@W1b + b (accumulate)
    k_gemm<false,false><<<gUV, 256, 0, stream>>>(feats, D, ag_w1,               D, nullptr, xh1, D, D);
    k_gemm<true ,true ><<<gUV, 256, 0, stream>>>(red,   D, ag_w1 + (size_t)D*D, D, ag_b1,  xh1, D, D);
    k_gemm<true ,false><<<gUV, 256, 0, stream>>>(xh1,   D, ag_w2, D, ag_b2, xh2, D, D);
    k_gemm<false,false><<<gUV, 256, 0, stream>>>(xh2,   D, ag_w3, D, ag_b3, xf,  D, D);

    // 4) sigmoid heads
    k_final<<<BS*NP, 256, 0, stream>>>(xf, subject, obj, cs_w, cs_b, cso_w, cso_b, out);
}

// Round 6
// 970.405 us; speedup vs baseline: 2.6866x; 1.1534x over previous
//
#include <hip/hip_runtime.h>
#include <hip/hip_bf16.h>
#include <math.h>

#define D 1024
#define NP 128
#define BS 2
#define GEO 64
#define TOPKN 18
#define NPAIR (BS*NP*NP)   // 32768

__device__ __forceinline__ float relu_(float x){ return fmaxf(x, 0.f); }
__device__ __forceinline__ unsigned short f2b(float x){
    __hip_bfloat16 h = __float2bfloat16(x);
    return *(unsigned short*)&h;
}
__device__ __forceinline__ float b2f(unsigned short u){
    return __uint_as_float((unsigned)u << 16);
}

typedef short bf16x8 __attribute__((ext_vector_type(8)));
typedef float f32x4  __attribute__((ext_vector_type(4)));

// ---------------- geo embedding + 3x Linear(64,64) MLP (chunk-local) ----------
__global__ __launch_bounds__(256) void k_geo(
    const float* __restrict__ prop,
    const float* __restrict__ gw1, const float* __restrict__ gb1,
    const float* __restrict__ gw2, const float* __restrict__ gb2,
    const float* __restrict__ gw3, const float* __restrict__ gb3,
    float* __restrict__ geoPc, int pofs)
{
    __shared__ float w[3][GEO*GEO];
    __shared__ float bias[3][GEO];
    int tid = threadIdx.x;
    for (int idx = tid; idx < GEO*GEO; idx += 256) {
        w[0][idx] = gw1[idx]; w[1][idx] = gw2[idx]; w[2][idx] = gw3[idx];
    }
    if (tid < GEO) { bias[0][tid]=gb1[tid]; bias[1][tid]=gb2[tid]; bias[2][tid]=gb3[tid]; }
    __syncthreads();
    int lane = tid & 63;
    int wave = tid >> 6;
    int gwave = blockIdx.x*4 + wave;     // chunk-local pair index
    int pair  = pofs + gwave;            // global pair index
    int p = lane >> 4;
    int s = lane & 15;
    int f = s & 7;
    float dm = expf((float)f * (6.907755278982137f/8.0f)); // 1000^(f/8)
    bool is_cos = (s & 8) != 0;
    float scale = 100.f / dm;

    int b  = pair >> 14;
    int ij = pair & 16383;
    int i  = ij >> 7;
    int j  = ij & 127;
    float4 pi = *(const float4*)(prop + (size_t)(b*NP + i)*4);
    float4 pj = *(const float4*)(prop + (size_t)(b*NP + j)*4);
    float wi  = pi.z-pi.x+1.f, hi_ = pi.w-pi.y+1.f;
    float wj  = pj.z-pj.x+1.f, hj  = pj.w-pj.y+1.f;
    float pos;
    if      (p == 0) pos = (0.5f*(pi.x+pi.z) - 0.5f*(pj.x+pj.z)) / wj;
    else if (p == 1) pos = (0.5f*(pi.y+pi.w) - 0.5f*(pj.y+pj.w)) / hj;
    else if (p == 2) pos = wi / wj;
    else             pos = hi_ / hj;
    pos = logf(fmaxf(fabsf(pos), 1e-3f));
    float dv = pos * scale;
    float v = is_cos ? cosf(dv) : sinf(dv);
    #pragma unroll
    for (int layer = 0; layer < 3; ++layer) {
        float acc = bias[layer][lane];
        for (int k = 0; k < GEO; ++k) {
            float vk = __shfl(v, k, 64);
            acc = fmaf(vk, w[layer][k*GEO + lane], acc);
        }
        v = (layer < 2) ? relu_(acc) : acc;
    }
    geoPc[(size_t)gwave*GEO + lane] = v;
}

// ---------------- small-M f32 GEMM: C = act(A@W + bias) ----------------
// A = [A1 | A2] row-major (K1 + K2 cols, K2 may be 0). W [K, N] f32.
// tile 16x64, BK=64, double-buffered LDS with register prefetch.
// grid (M/16, N/64, Z): z selects W slice (wz_stride) and C0/C1.
template<bool RELU>
__global__ __launch_bounds__(256) void k_sgemm(
    const float* __restrict__ A1, const float* __restrict__ A2,
    int K1, int K2,
    const float* __restrict__ W, size_t wz_stride,
    const float* __restrict__ bias,
    float* __restrict__ C0, float* __restrict__ C1, int N)
{
    __shared__ float As[2][16][64];
    __shared__ float Bs[2][64][64];
    const float* Wz = W + wz_stride * blockIdx.z;
    float* C = blockIdx.z ? C1 : C0;
    int t = threadIdx.x;
    int m0 = blockIdx.x * 16, n0 = blockIdx.y * 64;
    int am = t & 15, ak = (t >> 4) * 4;        // A stage: row am, k-offset ak
    int bn = (t & 15) * 4, bk = (t >> 4) * 4;  // B stage: k-rows bk.., col bn
    int tx = t & 15, ty = t >> 4;              // output: row ty, cols tx*4..
    int K = K1 + K2;
    int niter = K >> 6;
    float4 aR; float4 bR[4];
    auto g2r = [&](int i){
        int kg = (i << 6) + ak;
        aR = (kg < K1) ? *(const float4*)(A1 + (size_t)(m0+am)*K1 + kg)
                       : *(const float4*)(A2 + (size_t)(m0+am)*K2 + (kg - K1));
        int k0 = i << 6;
        #pragma unroll
        for (int r = 0; r < 4; ++r)
            bR[r] = *(const float4*)(Wz + (size_t)(k0 + bk + r)*N + n0 + bn);
    };
    auto r2lds = [&](int b){
        *(float4*)&As[b][am][ak] = aR;
        #pragma unroll
        for (int r = 0; r < 4; ++r)
            *(float4*)&Bs[b][bk + r][bn] = bR[r];
    };
    f32x4 acc = {0.f, 0.f, 0.f, 0.f};
    g2r(0); r2lds(0); __syncthreads();
    for (int i = 0; i < niter; ++i) {
        bool more = (i + 1) < niter;
        if (more) g2r(i + 1);
        int b = i & 1;
        #pragma unroll
        for (int k4 = 0; k4 < 16; ++k4) {
            float4 a4 = *(const float4*)&As[b][ty][k4*4];
            f32x4 b0 = *(const f32x4*)&Bs[b][k4*4+0][tx*4];
            f32x4 b1 = *(const f32x4*)&Bs[b][k4*4+1][tx*4];
            f32x4 b2 = *(const f32x4*)&Bs[b][k4*4+2][tx*4];
            f32x4 b3 = *(const f32x4*)&Bs[b][k4*4+3][tx*4];
            acc += a4.x * b0;
            acc += a4.y * b1;
            acc += a4.z * b2;
            acc += a4.w * b3;
        }
        if (more) { r2lds((i + 1) & 1); __syncthreads(); }
    }
    float4 bv4 = make_float4(0.f, 0.f, 0.f, 0.f);
    if (bias) bv4 = *(const float4*)(bias + n0 + tx*4);
    float4 o;
    o.x = acc[0] + bv4.x; o.y = acc[1] + bv4.y;
    o.z = acc[2] + bv4.z; o.w = acc[3] + bv4.w;
    if (RELU) { o.x=relu_(o.x); o.y=relu_(o.y); o.z=relu_(o.z); o.w=relu_(o.w); }
    *(float4*)(C + (size_t)(m0 + ty)*N + n0 + tx*4) = o;
}

// ---------------- transpose + f32->bf16: WT[n][k] = bf16(W[k][n]) ----------------
__global__ __launch_bounds__(256) void k_wT(const float* __restrict__ W,
                                            unsigned short* __restrict__ WT,
                                            int K, int N)
{
    __shared__ float tile[64][65];
    int bx = blockIdx.x;  // along N
    int by = blockIdx.y;  // along K
    int t = threadIdx.x;
    int tc = t & 63, tr = t >> 6;
    #pragma unroll
    for (int r = tr; r < 64; r += 4)
        tile[r][tc] = W[(size_t)(by*64 + r)*N + bx*64 + tc];
    __syncthreads();
    #pragma unroll
    for (int r = tr; r < 64; r += 4)
        WT[(size_t)(bx*64 + r)*K + by*64 + tc] = f2b(tile[tc][r]);
}

// ---------------- bf16 MFMA GEMM: C[M,N] = act(A@B + bias) ----------------
// A [M,K] bf16 row-major; BT [N,K] bf16 row-major (i.e. B transposed).
// 128x128 block tile, 4 waves (2x2), each wave 64x64 via 4x4 of 16x16x32 MFMA.
#define LDST 40   // LDS row stride in bf16 (16B-aligned, bank-spread)
template<bool RELU, bool OUT_BF16>
__global__ __launch_bounds__(256) void k_mgemm(
    const unsigned short* __restrict__ A,
    const unsigned short* __restrict__ BT,
    const float* __restrict__ bias,
    void* __restrict__ Cv, int M, int N, int K)
{
    __shared__ unsigned short As[128*LDST];
    __shared__ unsigned short Bs[128*LDST];
    int t  = threadIdx.x;
    int m0 = blockIdx.x * 128;
    int n0 = blockIdx.y * 128;
    int w  = t >> 6, l = t & 63;
    int wm = w & 1, wn = w >> 1;
    int lr = l & 15;      // row-in-16 (A) / col-in-16 (B)
    int lq = l >> 4;      // quad -> k-offset lq*8

    int c0 = t, c1 = t + 256;
    int r0 = c0 >> 2, ko0 = (c0 & 3) * 8;
    int r1 = c1 >> 2, ko1 = (c1 & 3) * 8;

    f32x4 acc[4][4];
    #pragma unroll
    for (int mi = 0; mi < 4; ++mi)
        #pragma unroll
        for (int ni = 0; ni < 4; ++ni)
            #pragma unroll
            for (int r = 0; r < 4; ++r) acc[mi][ni][r] = 0.f;

    for (int k0 = 0; k0 < K; k0 += 32) {
        __syncthreads();
        *(bf16x8*)(As + r0*LDST + ko0) = *(const bf16x8*)(A  + (size_t)(m0 + r0)*K + k0 + ko0);
        *(bf16x8*)(As + r1*LDST + ko1) = *(const bf16x8*)(A  + (size_t)(m0 + r1)*K + k0 + ko1);
        *(bf16x8*)(Bs + r0*LDST + ko0) = *(const bf16x8*)(BT + (size_t)(n0 + r0)*K + k0 + ko0);
        *(bf16x8*)(Bs + r1*LDST + ko1) = *(const bf16x8*)(BT + (size_t)(n0 + r1)*K + k0 + ko1);
        __syncthreads();
        bf16x8 af[4], bf[4];
        #pragma unroll
        for (int mi = 0; mi < 4; ++mi)
            af[mi] = *(const bf16x8*)(As + (wm*64 + mi*16 + lr)*LDST + lq*8);
        #pragma unroll
        for (int ni = 0; ni < 4; ++ni)
            bf[ni] = *(const bf16x8*)(Bs + (wn*64 + ni*16 + lr)*LDST + lq*8);
        #pragma unroll
        for (int mi = 0; mi < 4; ++mi)
            #pragma unroll
            for (int ni = 0; ni < 4; ++ni)
                acc[mi][ni] = __builtin_amdgcn_mfma_f32_16x16x32_bf16(af[mi], bf[ni], acc[mi][ni], 0, 0, 0);
    }

    #pragma unroll
    for (int mi = 0; mi < 4; ++mi) {
        #pragma unroll
        for (int ni = 0; ni < 4; ++ni) {
            int gc = n0 + wn*64 + ni*16 + lr;
            int gr = m0 + wm*64 + mi*16 + lq*4;
            float bval = bias ? bias[gc] : 0.f;
            #pragma unroll
            for (int r = 0; r < 4; ++r) {
                float v = acc[mi][ni][r] + bval;
                if (RELU) v = relu_(v);
                if (OUT_BF16) ((unsigned short*)Cv)[(size_t)(gr + r)*N + gc] = f2b(v);
                else          ((float*)Cv)[(size_t)(gr + r)*N + gc] = v;
            }
        }
    }
}

// ---------------- h1 = relu(U[b,j] + V[b,i] + geoPc@W1c + b1) -> bf16 ----------
__global__ __launch_bounds__(256) void k_h1(
    const float* __restrict__ geoPc, const float* __restrict__ W1c,
    const float* __restrict__ b1,
    const float* __restrict__ U, const float* __restrict__ V,
    unsigned short* __restrict__ h1c, int pofs)
{
    __shared__ float g[8][GEO];
    int pl    = blockIdx.x * 8;
    int pbase = pofs + pl;
    int b  = pbase >> 14;
    int ij = pbase & 16383;
    int i  = ij >> 7;
    int j0 = ij & 127;
    int tid = threadIdx.x;
    for (int t = tid; t < 8*GEO; t += 256) ((float*)g)[t] = geoPc[(size_t)pl*GEO + t];
    __syncthreads();
    int c = tid * 4;
    float4 base4 = *(const float4*)(b1 + c);
    float4 vv = *(const float4*)(V + (size_t)(b*NP + i)*D + c);
    base4.x += vv.x; base4.y += vv.y; base4.z += vv.z; base4.w += vv.w;
    float4 acc[8];
    #pragma unroll
    for (int pp = 0; pp < 8; ++pp) {
        float4 uu = *(const float4*)(U + (size_t)(b*NP + j0 + pp)*D + c);
        acc[pp].x = base4.x + uu.x; acc[pp].y = base4.y + uu.y;
        acc[pp].z = base4.z + uu.z; acc[pp].w = base4.w + uu.w;
    }
    for (int k = 0; k < GEO; ++k) {
        float4 w4 = *(const float4*)(W1c + (size_t)k*D + c);
        #pragma unroll
        for (int pp = 0; pp < 8; ++pp) {
            float gk = g[pp][k];
            acc[pp].x = fmaf(gk, w4.x, acc[pp].x);
            acc[pp].y = fmaf(gk, w4.y, acc[pp].y);
            acc[pp].z = fmaf(gk, w4.z, acc[pp].z);
            acc[pp].w = fmaf(gk, w4.w, acc[pp].w);
        }
    }
    #pragma unroll
    for (int pp = 0; pp < 8; ++pp) {
        ushort4 o;
        o.x = f2b(relu_(acc[pp].x)); o.y = f2b(relu_(acc[pp].y));
        o.z = f2b(relu_(acc[pp].z)); o.w = f2b(relu_(acc[pp].w));
        *(ushort4*)(h1c + (size_t)(pl + pp)*D + c) = o;
    }
}

// ---------------- top-18 over j, sum/8 (per chunk of CH rows), bf16 in ----------
__global__ __launch_bounds__(256) void k_topk(const unsigned short* __restrict__ fc,
                                              float* __restrict__ red_out)
{
    int gid = blockIdx.x*256 + threadIdx.x;
    int c  = gid & (D-1);
    int bl = gid >> 10;
    const unsigned short* base = fc + (size_t)bl*NP*D + c;
    float sm[TOPKN];
    #pragma unroll
    for (int t = 0; t < TOPKN; ++t) sm[t] = -INFINITY;
    for (int j = 0; j < NP; ++j) {
        float v = b2f(base[(size_t)j*D]);
        #pragma unroll
        for (int t = 0; t < TOPKN; ++t) {
            float mx = fmaxf(sm[t], v);
            v = fminf(sm[t], v);
            sm[t] = mx;
        }
    }
    float ssum = 0.f;
    #pragma unroll
    for (int t = 0; t < TOPKN; ++t) ssum += sm[t];
    red_out[gid] = ssum * 0.125f;
}

// ---------------- final heads -> sigmoid, f32 out ----------------
__global__ __launch_bounds__(256) void k_final(const float* __restrict__ x,
    const float* __restrict__ subject, const float* __restrict__ obj,
    const float* __restrict__ cs_w, const float* __restrict__ cs_b,
    const float* __restrict__ cso_w, const float* __restrict__ cso_b,
    float* __restrict__ out)
{
    int bi = blockIdx.x;
    int b  = bi >> 7;
    const float* xr = x + (size_t)bi*D;
    const float* sb = subject + (size_t)b*D;
    const float* ob = obj + (size_t)b*D;
    int tid = threadIdx.x;
    float a0 = 0.f, a1 = 0.f;
    for (int k = tid; k < D; k += 256) {
        float xv = xr[k];
        a0 = fmaf(xv, cs_w[k], a0);
        a0 = fmaf(sb[k], cs_w[D+k], a0);
        a1 = fmaf(xv, cso_w[k], a1);
        a1 = fmaf(ob[k], cso_w[D+k], a1);
    }
    __shared__ float r0[256], r1[256];
    r0[tid] = a0; r1[tid] = a1;
    __syncthreads();
    for (int s2 = 128; s2 > 0; s2 >>= 1) {
        if (tid < s2) { r0[tid] += r0[tid+s2]; r1[tid] += r1[tid+s2]; }
        __syncthreads();
    }
    if (tid == 0) {
        out[bi*2+0] = 1.f/(1.f + expf(-(r0[0] + cs_b[0])));
        out[bi*2+1] = 1.f/(1.f + expf(-(r1[0] + cso_b[0])));
    }
}

extern "C" void kernel_launch(void* const* d_in, const int* in_sizes, int n_in,
                              void* d_out, int out_size, void* d_ws, size_t ws_size,
                              hipStream_t stream)
{
    const float* feats   = (const float*)d_in[0];
    const float* subject = (const float*)d_in[1];
    const float* obj     = (const float*)d_in[2];
    const float* prop    = (const float*)d_in[3];
    const float* gp_w1 = (const float*)d_in[4];  const float* gp_b1 = (const float*)d_in[5];
    const float* gp_w2 = (const float*)d_in[6];  const float* gp_b2 = (const float*)d_in[7];
    const float* gp_w3 = (const float*)d_in[8];  const float* gp_b3 = (const float*)d_in[9];
    const float* pm_w1 = (const float*)d_in[10]; const float* pm_b1 = (const float*)d_in[11];
    const float* pm_w2 = (const float*)d_in[12]; const float* pm_b2 = (const float*)d_in[13];
    const float* pm_w3 = (const float*)d_in[14]; const float* pm_b3 = (const float*)d_in[15];
    const float* ag_w1 = (const float*)d_in[16]; const float* ag_b1 = (const float*)d_in[17];
    const float* ag_w2 = (const float*)d_in[18]; const float* ag_b2 = (const float*)d_in[19];
    const float* ag_w3 = (const float*)d_in[20]; const float* ag_b3 = (const float*)d_in[21];
    const float* cs_w  = (const float*)d_in[22]; const float* cs_b  = (const float*)d_in[23];
    const float* cso_w = (const float*)d_in[24]; const float* cso_b = (const float*)d_in[25];
    float* out = (float*)d_out;

    // ---- workspace layout (bytes) ----
    char* wsb = (char*)d_ws;
    size_t off = 0;
    auto alloc = [&](size_t bytes) { char* p = wsb + off; off += (bytes + 255) & ~255ull; return p; };
    float* Ub  = (float*)alloc((size_t)BS*NP*D*4);
    float* Vb  = (float*)alloc((size_t)BS*NP*D*4);
    float* red = (float*)alloc((size_t)BS*NP*D*4);
    float* xh1 = (float*)alloc((size_t)BS*NP*D*4);
    float* xh2 = (float*)alloc((size_t)BS*NP*D*4);
    float* xf  = (float*)alloc((size_t)BS*NP*D*4);
    unsigned short* w2T = (unsigned short*)alloc((size_t)D*D*2);
    unsigned short* w3T = (unsigned short*)alloc((size_t)D*D*2);
    size_t persist = off;

    // chunk: geoPc f32 + h1c bf16 + h2c bf16 + fcb bf16
    size_t chunk_unit = (size_t)NP*(GEO*4 + D*2 + D*2 + D*2);
    int CH = 64;
    while (CH > 1 && persist + (size_t)CH*chunk_unit + 4096 > ws_size) CH >>= 1;
    float*          geoPc = (float*)(wsb + persist);
    unsigned short* h1c   = (unsigned short*)((char*)geoPc + (size_t)CH*NP*GEO*4);
    unsigned short* h2c   = (unsigned short*)((char*)h1c   + (size_t)CH*NP*D*2);
    unsigned short* fcb   = (unsigned short*)((char*)h2c   + (size_t)CH*NP*D*2);

    const float* W1c = pm_w1 + (size_t)2*D*D;   // geo slice of pm_w1

    // 0) weights -> bf16 transposed
    dim3 gT(D/64, D/64);
    k_wT<<<gT, 256, 0, stream>>>(pm_w2, w2T, D, D);
    k_wT<<<gT, 256, 0, stream>>>(pm_w3, w3T, D, D);

    // 1) U = feats @ pm_w1[0:1024,:] ; V = feats @ pm_w1[1024:2048,:]  (one dispatch, z=2)
    dim3 gUV(BS*NP/16, D/64, 2);
    k_sgemm<false><<<gUV, 256, 0, stream>>>(feats, nullptr, D, 0,
                                            pm_w1, (size_t)D*D, nullptr, Ub, Vb, D);

    // 2) chunked over (b,i) rows: geo -> h1(bf16) -> h2(bf16,MFMA) -> fet(bf16,MFMA) -> topk
    int nchunks = (BS*NP)/CH;
    for (int cchunk = 0; cchunk < nchunks; ++cchunk) {
        int bi0  = cchunk * CH;
        int pofs = bi0 * NP;
        k_geo<<<CH*NP/4, 256, 0, stream>>>(prop, gp_w1, gp_b1, gp_w2, gp_b2, gp_w3, gp_b3, geoPc, pofs);
        k_h1<<<CH*NP/8, 256, 0, stream>>>(geoPc, W1c, pm_b1, Ub, Vb, h1c, pofs);
        dim3 gBig(CH*NP/128, D/128);
        k_mgemm<true ,true><<<gBig, 256, 0, stream>>>(h1c, w2T, pm_b2, h2c, CH*NP, D, D);
        k_mgemm<false,true><<<gBig, 256, 0, stream>>>(h2c, w3T, pm_b3, fcb, CH*NP, D, D);
        k_topk<<<CH*D/256, 256, 0, stream>>>(fcb, red + (size_t)bi0*D);
    }

    // 3) aggregate MLP: layer1 with fused [feats|red] concat (K=2048), then 2 more layers
    dim3 gAg(BS*NP/16, D/64, 1);
    k_sgemm<true ><<<gAg, 256, 0, stream>>>(feats, red, D, D,
                                            ag_w1, 0, ag_b1, xh1, nullptr, D);
    k_sgemm<true ><<<gAg, 256, 0, stream>>>(xh1, nullptr, D, 0,
                                            ag_w2, 0, ag_b2, xh2, nullptr, D);
    k_sgemm<false><<<gAg, 256, 0, stream>>>(xh2, nullptr, D, 0,
                                            ag_w3, 0, ag_b3, xf, nullptr, D);

    // 4) sigmoid heads
    k_final<<<BS*NP, 256, 0, stream>>>(xf, subject, obj, cs_w, cs_b, cso_w, cso_b, out);
}

// Round 7
// 799.894 us; speedup vs baseline: 3.2593x; 1.2132x over previous
//
#include <hip/hip_runtime.h>
#include <hip/hip_bf16.h>
#include <math.h>

#define D 1024
#define NP 128
#define BS 2
#define GEO 64
#define TOPKN 18
#define NPAIR (BS*NP*NP)   // 32768

__device__ __forceinline__ float relu_(float x){ return fmaxf(x, 0.f); }
__device__ __forceinline__ unsigned short f2b(float x){
    __hip_bfloat16 h = __float2bfloat16(x);
    return *(unsigned short*)&h;
}
__device__ __forceinline__ float b2f(unsigned short u){
    return __uint_as_float((unsigned)u << 16);
}

typedef short bf16x8 __attribute__((ext_vector_type(8)));
typedef float f32x4  __attribute__((ext_vector_type(4)));

// async global->LDS, 16B per lane. LDS dest must be wave-uniform base + lane*16.
__device__ __forceinline__ void glds16(const unsigned short* g, unsigned short* l){
    __builtin_amdgcn_global_load_lds(
        (const __attribute__((address_space(1))) void*)g,
        (__attribute__((address_space(3))) void*)l,
        16, 0, 0);
}

// ---------------- geo embedding + 3x Linear(64,64) MLP (chunk-local) ----------
__global__ __launch_bounds__(256) void k_geo(
    const float* __restrict__ prop,
    const float* __restrict__ gw1, const float* __restrict__ gb1,
    const float* __restrict__ gw2, const float* __restrict__ gb2,
    const float* __restrict__ gw3, const float* __restrict__ gb3,
    float* __restrict__ geoPc, int pofs)
{
    __shared__ float w[3][GEO*GEO];
    __shared__ float bias[3][GEO];
    int tid = threadIdx.x;
    for (int idx = tid; idx < GEO*GEO; idx += 256) {
        w[0][idx] = gw1[idx]; w[1][idx] = gw2[idx]; w[2][idx] = gw3[idx];
    }
    if (tid < GEO) { bias[0][tid]=gb1[tid]; bias[1][tid]=gb2[tid]; bias[2][tid]=gb3[tid]; }
    __syncthreads();
    int lane = tid & 63;
    int wave = tid >> 6;
    int gwave = blockIdx.x*4 + wave;
    int pair  = pofs + gwave;
    int p = lane >> 4;
    int s = lane & 15;
    int f = s & 7;
    float dm = expf((float)f * (6.907755278982137f/8.0f)); // 1000^(f/8)
    bool is_cos = (s & 8) != 0;
    float scale = 100.f / dm;

    int b  = pair >> 14;
    int ij = pair & 16383;
    int i  = ij >> 7;
    int j  = ij & 127;
    float4 pi = *(const float4*)(prop + (size_t)(b*NP + i)*4);
    float4 pj = *(const float4*)(prop + (size_t)(b*NP + j)*4);
    float wi  = pi.z-pi.x+1.f, hi_ = pi.w-pi.y+1.f;
    float wj  = pj.z-pj.x+1.f, hj  = pj.w-pj.y+1.f;
    float pos;
    if      (p == 0) pos = (0.5f*(pi.x+pi.z) - 0.5f*(pj.x+pj.z)) / wj;
    else if (p == 1) pos = (0.5f*(pi.y+pi.w) - 0.5f*(pj.y+pj.w)) / hj;
    else if (p == 2) pos = wi / wj;
    else             pos = hi_ / hj;
    pos = logf(fmaxf(fabsf(pos), 1e-3f));
    float dv = pos * scale;
    float v = is_cos ? cosf(dv) : sinf(dv);
    #pragma unroll
    for (int layer = 0; layer < 3; ++layer) {
        float acc = bias[layer][lane];
        for (int k = 0; k < GEO; ++k) {
            float vk = __shfl(v, k, 64);
            acc = fmaf(vk, w[layer][k*GEO + lane], acc);
        }
        v = (layer < 2) ? relu_(acc) : acc;
    }
    geoPc[(size_t)gwave*GEO + lane] = v;
}

// ------------- batched weight transpose+bf16: 7 matrices, N=1024 cols -------------
struct WT7 {
    const float* src[7];
    unsigned short* dst[7];
    int kt[7];     // K/64
    int pre[8];    // prefix of tile counts (kt*16)
};
__global__ __launch_bounds__(256) void k_wTall(WT7 d)
{
    __shared__ float tile[64][65];
    int bid = blockIdx.x;
    int e = 0;
    while (e < 6 && bid >= d.pre[e+1]) ++e;
    int local = bid - d.pre[e];
    int bx = local & 15;      // n-tile (N=1024 -> 16 tiles)
    int by = local >> 4;      // k-tile
    int K = d.kt[e] * 64;
    const float* W = d.src[e];
    unsigned short* WT = d.dst[e];
    int t = threadIdx.x;
    int tc = t & 63, tr = t >> 6;
    #pragma unroll
    for (int r = tr; r < 64; r += 4)
        tile[r][tc] = W[(size_t)(by*64 + r)*1024 + bx*64 + tc];
    __syncthreads();
    #pragma unroll
    for (int r = tr; r < 64; r += 4)
        WT[(size_t)(bx*64 + r)*K + by*64 + tc] = f2b(tile[tc][r]);
}

// ---------------- split-K MFMA GEMM for M=256 layers ----------------
// A [M,K] (f32 concat A1|A2, or bf16 A1); BT [N,K] bf16. 16x128 tile.
// grid (M/16, N/128, NMAT*KZ). Writes f32 partials Cp[bz][M][N].
template<bool A_F32>
__global__ __launch_bounds__(256) void k_skmm(
    const void* __restrict__ A1v, const void* __restrict__ A2v,
    int K1, int K2,
    const unsigned short* __restrict__ BT0,
    const unsigned short* __restrict__ BT1,
    float* __restrict__ Cp,
    int KZ, int Kc, int N)
{
    __shared__ unsigned short As[16*32];
    __shared__ unsigned short Bs[128*32];
    int t = threadIdx.x;
    int m0 = blockIdx.x * 16;
    int n0 = blockIdx.y * 128;
    int bz = blockIdx.z;
    int kz = bz % KZ;
    int mat = bz / KZ;
    const unsigned short* BT = mat ? BT1 : BT0;
    int K = K1 + K2;
    int M = gridDim.x * 16;
    int w = t >> 6, l = t & 63;
    int lr = l & 15, lq = l >> 4;
    int arow = t >> 3, ak = (t & 7) * 4;     // A_F32 staging (128 threads)
    int arow2 = t >> 2, ak2 = (t & 3) * 8;   // A_BF16 staging (64 threads)
    int brow = t >> 1, bk = (t & 1) * 16;    // B staging (all threads)
    f32x4 acc0 = {0.f,0.f,0.f,0.f}, acc1 = {0.f,0.f,0.f,0.f};
    for (int i = 0; i < Kc; i += 32) {
        int kg0 = kz*Kc + i;
        __syncthreads();
        if (A_F32) {
            if (t < 128) {
                int kg = kg0 + ak;
                const float* src = (kg < K1)
                    ? (const float*)A1v + (size_t)(m0+arow)*K1 + kg
                    : (const float*)A2v + (size_t)(m0+arow)*K2 + (kg - K1);
                float4 a4 = *(const float4*)src;
                ushort4 u;
                u.x=f2b(a4.x); u.y=f2b(a4.y); u.z=f2b(a4.z); u.w=f2b(a4.w);
                *(ushort4*)(As + arow*32 + ak) = u;
            }
        } else {
            if (t < 64) {
                const unsigned short* src = (const unsigned short*)A1v + (size_t)(m0+arow2)*K1 + kg0 + ak2;
                *(bf16x8*)(As + arow2*32 + ak2) = *(const bf16x8*)src;
            }
        }
        const unsigned short* srcb = BT + (size_t)(n0+brow)*K + kg0 + bk;
        *(bf16x8*)(Bs + brow*32 + bk)     = *(const bf16x8*)srcb;
        *(bf16x8*)(Bs + brow*32 + bk + 8) = *(const bf16x8*)(srcb + 8);
        __syncthreads();
        bf16x8 af = *(const bf16x8*)(As + lr*32 + lq*8);
        bf16x8 b0 = *(const bf16x8*)(Bs + (w*32      + lr)*32 + lq*8);
        bf16x8 b1 = *(const bf16x8*)(Bs + (w*32 + 16 + lr)*32 + lq*8);
        acc0 = __builtin_amdgcn_mfma_f32_16x16x32_bf16(af, b0, acc0, 0, 0, 0);
        acc1 = __builtin_amdgcn_mfma_f32_16x16x32_bf16(af, b1, acc1, 0, 0, 0);
    }
    float* Co = Cp + (size_t)bz*M*N;
    #pragma unroll
    for (int r = 0; r < 4; ++r) {
        int gr = m0 + lq*4 + r;
        Co[(size_t)gr*N + n0 + w*32      + lr] = acc0[r];
        Co[(size_t)gr*N + n0 + w*32 + 16 + lr] = acc1[r];
    }
}

// ---------------- reduce split-K partials: out = act(sum + bias) ----------------
template<bool RELU, bool OUT_BF16>
__global__ __launch_bounds__(256) void k_red(
    const float* __restrict__ Cp, int KZ,
    const float* __restrict__ bias,
    void* __restrict__ out0, void* __restrict__ out1,
    int MN, int N)
{
    int z = blockIdx.z;
    const float* C = Cp + (size_t)z*KZ*MN;
    void* out = z ? out1 : out0;
    int idx = (blockIdx.x*256 + threadIdx.x) * 4;
    f32x4 s = {0.f,0.f,0.f,0.f};
    for (int k = 0; k < KZ; ++k)
        s += *(const f32x4*)(C + (size_t)k*MN + idx);
    if (bias) s += *(const f32x4*)(bias + (idx & (N-1)));
    if (RELU) { s[0]=relu_(s[0]); s[1]=relu_(s[1]); s[2]=relu_(s[2]); s[3]=relu_(s[3]); }
    if (OUT_BF16) {
        ushort4 u; u.x=f2b(s[0]); u.y=f2b(s[1]); u.z=f2b(s[2]); u.w=f2b(s[3]);
        *(ushort4*)((unsigned short*)out + idx) = u;
    } else {
        float4 o; o.x=s[0]; o.y=s[1]; o.z=s[2]; o.w=s[3];
        *(float4*)((float*)out + idx) = o;
    }
}

// ---------------- bf16 MFMA GEMM (m97 structure): C = act(A@B + bias) ----------
// A [M,K] bf16; BT [N,K] bf16. 128x128 tile, 4 waves 2x2, BK=32,
// unpadded LDS (stride 32) + global_load_lds width-16 staging, 2-barrier loop.
template<bool RELU, bool OUT_BF16>
__global__ __launch_bounds__(256) void k_mgemm(
    const unsigned short* __restrict__ A,
    const unsigned short* __restrict__ BT,
    const float* __restrict__ bias,
    void* __restrict__ Cv, int M, int N, int K)
{
    __shared__ unsigned short As[128*32];
    __shared__ unsigned short Bs[128*32];
    int t  = threadIdx.x;
    int m0 = blockIdx.x * 128;
    int n0 = blockIdx.y * 128;
    int w  = t >> 6, l = t & 63;
    int wm = w & 1, wn = w >> 1;
    int lr = l & 15;
    int lq = l >> 4;

    // glds staging: 8 segments of 16 rows; wave w stages segments 2w, 2w+1.
    int s0 = w*2, s1 = w*2 + 1;
    int srow = l >> 2;              // row within segment
    int sko  = (l & 3) * 8;         // k-offset (elems)
    int rowA0 = s0*16 + srow, rowA1 = s1*16 + srow;
    unsigned short* ldsA0 = As + s0*512 + l*8;
    unsigned short* ldsA1 = As + s1*512 + l*8;
    unsigned short* ldsB0 = Bs + s0*512 + l*8;
    unsigned short* ldsB1 = Bs + s1*512 + l*8;

    f32x4 acc[4][4];
    #pragma unroll
    for (int mi = 0; mi < 4; ++mi)
        #pragma unroll
        for (int ni = 0; ni < 4; ++ni)
            #pragma unroll
            for (int r = 0; r < 4; ++r) acc[mi][ni][r] = 0.f;

    for (int k0 = 0; k0 < K; k0 += 32) {
        glds16(A  + (size_t)(m0 + rowA0)*K + k0 + sko, ldsA0);
        glds16(A  + (size_t)(m0 + rowA1)*K + k0 + sko, ldsA1);
        glds16(BT + (size_t)(n0 + rowA0)*K + k0 + sko, ldsB0);
        glds16(BT + (size_t)(n0 + rowA1)*K + k0 + sko, ldsB1);
        __syncthreads();   // drains vmcnt (glds) before LDS reads
        bf16x8 af[4], bf[4];
        #pragma unroll
        for (int mi = 0; mi < 4; ++mi)
            af[mi] = *(const bf16x8*)(As + (wm*64 + mi*16 + lr)*32 + lq*8);
        #pragma unroll
        for (int ni = 0; ni < 4; ++ni)
            bf[ni] = *(const bf16x8*)(Bs + (wn*64 + ni*16 + lr)*32 + lq*8);
        #pragma unroll
        for (int mi = 0; mi < 4; ++mi)
            #pragma unroll
            for (int ni = 0; ni < 4; ++ni)
                acc[mi][ni] = __builtin_amdgcn_mfma_f32_16x16x32_bf16(af[mi], bf[ni], acc[mi][ni], 0, 0, 0);
        __syncthreads();   // protect LDS from next iteration's glds
    }

    #pragma unroll
    for (int mi = 0; mi < 4; ++mi) {
        #pragma unroll
        for (int ni = 0; ni < 4; ++ni) {
            int gc = n0 + wn*64 + ni*16 + lr;
            int gr = m0 + wm*64 + mi*16 + lq*4;
            float bval = bias ? bias[gc] : 0.f;
            #pragma unroll
            for (int r = 0; r < 4; ++r) {
                float v = acc[mi][ni][r] + bval;
                if (RELU) v = relu_(v);
                if (OUT_BF16) ((unsigned short*)Cv)[(size_t)(gr + r)*N + gc] = f2b(v);
                else          ((float*)Cv)[(size_t)(gr + r)*N + gc] = v;
            }
        }
    }
}

// ---------------- h1 = relu(U[b,j] + V[b,i] + geoPc@W1c + b1) -> bf16 ----------
__global__ __launch_bounds__(256) void k_h1(
    const float* __restrict__ geoPc, const float* __restrict__ W1c,
    const float* __restrict__ b1,
    const float* __restrict__ U, const float* __restrict__ V,
    unsigned short* __restrict__ h1c, int pofs)
{
    __shared__ float g[8][GEO];
    int pl    = blockIdx.x * 8;
    int pbase = pofs + pl;
    int b  = pbase >> 14;
    int ij = pbase & 16383;
    int i  = ij >> 7;
    int j0 = ij & 127;
    int tid = threadIdx.x;
    for (int t = tid; t < 8*GEO; t += 256) ((float*)g)[t] = geoPc[(size_t)pl*GEO + t];
    __syncthreads();
    int c = tid * 4;
    float4 base4 = *(const float4*)(b1 + c);
    float4 vv = *(const float4*)(V + (size_t)(b*NP + i)*D + c);
    base4.x += vv.x; base4.y += vv.y; base4.z += vv.z; base4.w += vv.w;
    float4 acc[8];
    #pragma unroll
    for (int pp = 0; pp < 8; ++pp) {
        float4 uu = *(const float4*)(U + (size_t)(b*NP + j0 + pp)*D + c);
        acc[pp].x = base4.x + uu.x; acc[pp].y = base4.y + uu.y;
        acc[pp].z = base4.z + uu.z; acc[pp].w = base4.w + uu.w;
    }
    for (int k = 0; k < GEO; ++k) {
        float4 w4 = *(const float4*)(W1c + (size_t)k*D + c);
        #pragma unroll
        for (int pp = 0; pp < 8; ++pp) {
            float gk = g[pp][k];
            acc[pp].x = fmaf(gk, w4.x, acc[pp].x);
            acc[pp].y = fmaf(gk, w4.y, acc[pp].y);
            acc[pp].z = fmaf(gk, w4.z, acc[pp].z);
            acc[pp].w = fmaf(gk, w4.w, acc[pp].w);
        }
    }
    #pragma unroll
    for (int pp = 0; pp < 8; ++pp) {
        ushort4 o;
        o.x = f2b(relu_(acc[pp].x)); o.y = f2b(relu_(acc[pp].y));
        o.z = f2b(relu_(acc[pp].z)); o.w = f2b(relu_(acc[pp].w));
        *(ushort4*)(h1c + (size_t)(pl + pp)*D + c) = o;
    }
}

// ---------------- top-18 over j, sum/8 (per chunk of CH rows), bf16 in ----------
__global__ __launch_bounds__(256) void k_topk(const unsigned short* __restrict__ fc,
                                              float* __restrict__ red_out)
{
    int gid = blockIdx.x*256 + threadIdx.x;
    int c  = gid & (D-1);
    int bl = gid >> 10;
    const unsigned short* base = fc + (size_t)bl*NP*D + c;
    float sm[TOPKN];
    #pragma unroll
    for (int t = 0; t < TOPKN; ++t) sm[t] = -INFINITY;
    for (int j = 0; j < NP; ++j) {
        float v = b2f(base[(size_t)j*D]);
        #pragma unroll
        for (int t = 0; t < TOPKN; ++t) {
            float mx = fmaxf(sm[t], v);
            v = fminf(sm[t], v);
            sm[t] = mx;
        }
    }
    float ssum = 0.f;
    #pragma unroll
    for (int t = 0; t < TOPKN; ++t) ssum += sm[t];
    red_out[gid] = ssum * 0.125f;
}

// ---------------- final heads -> sigmoid, f32 out ----------------
__global__ __launch_bounds__(256) void k_final(const float* __restrict__ x,
    const float* __restrict__ subject, const float* __restrict__ obj,
    const float* __restrict__ cs_w, const float* __restrict__ cs_b,
    const float* __restrict__ cso_w, const float* __restrict__ cso_b,
    float* __restrict__ out)
{
    int bi = blockIdx.x;
    int b  = bi >> 7;
    const float* xr = x + (size_t)bi*D;
    const float* sb = subject + (size_t)b*D;
    const float* ob = obj + (size_t)b*D;
    int tid = threadIdx.x;
    float a0 = 0.f, a1 = 0.f;
    for (int k = tid; k < D; k += 256) {
        float xv = xr[k];
        a0 = fmaf(xv, cs_w[k], a0);
        a0 = fmaf(sb[k], cs_w[D+k], a0);
        a1 = fmaf(xv, cso_w[k], a1);
        a1 = fmaf(ob[k], cso_w[D+k], a1);
    }
    __shared__ float r0[256], r1[256];
    r0[tid] = a0; r1[tid] = a1;
    __syncthreads();
    for (int s2 = 128; s2 > 0; s2 >>= 1) {
        if (tid < s2) { r0[tid] += r0[tid+s2]; r1[tid] += r1[tid+s2]; }
        __syncthreads();
    }
    if (tid == 0) {
        out[bi*2+0] = 1.f/(1.f + expf(-(r0[0] + cs_b[0])));
        out[bi*2+1] = 1.f/(1.f + expf(-(r1[0] + cso_b[0])));
    }
}

extern "C" void kernel_launch(void* const* d_in, const int* in_sizes, int n_in,
                              void* d_out, int out_size, void* d_ws, size_t ws_size,
                              hipStream_t stream)
{
    const float* feats   = (const float*)d_in[0];
    const float* subject = (const float*)d_in[1];
    const float* obj     = (const float*)d_in[2];
    const float* prop    = (const float*)d_in[3];
    const float* gp_w1 = (const float*)d_in[4];  const float* gp_b1 = (const float*)d_in[5];
    const float* gp_w2 = (const float*)d_in[6];  const float* gp_b2 = (const float*)d_in[7];
    const float* gp_w3 = (const float*)d_in[8];  const float* gp_b3 = (const float*)d_in[9];
    const float* pm_w1 = (const float*)d_in[10]; const float* pm_b1 = (const float*)d_in[11];
    const float* pm_w2 = (const float*)d_in[12]; const float* pm_b2 = (const float*)d_in[13];
    const float* pm_w3 = (const float*)d_in[14]; const float* pm_b3 = (const float*)d_in[15];
    const float* ag_w1 = (const float*)d_in[16]; const float* ag_b1 = (const float*)d_in[17];
    const float* ag_w2 = (const float*)d_in[18]; const float* ag_b2 = (const float*)d_in[19];
    const float* ag_w3 = (const float*)d_in[20]; const float* ag_b3 = (const float*)d_in[21];
    const float* cs_w  = (const float*)d_in[22]; const float* cs_b  = (const float*)d_in[23];
    const float* cso_w = (const float*)d_in[24]; const float* cso_b = (const float*)d_in[25];
    float* out = (float*)d_out;

    const int M = BS*NP;          // 256
    const int MN = M*D;           // 262144

    // ---- workspace layout (bytes) ----
    char* wsb = (char*)d_ws;
    size_t off = 0;
    auto alloc = [&](size_t bytes) { char* p = wsb + off; off += (bytes + 255) & ~255ull; return p; };
    float* Ub  = (float*)alloc((size_t)MN*4);
    float* Vb  = (float*)alloc((size_t)MN*4);
    float* red = (float*)alloc((size_t)MN*4);
    float* xf  = (float*)alloc((size_t)MN*4);
    unsigned short* xh1b = (unsigned short*)alloc((size_t)MN*2);
    unsigned short* xh2b = (unsigned short*)alloc((size_t)MN*2);
    unsigned short* w1aT = (unsigned short*)alloc((size_t)D*D*2);
    unsigned short* w1bT = (unsigned short*)alloc((size_t)D*D*2);
    unsigned short* w2T  = (unsigned short*)alloc((size_t)D*D*2);
    unsigned short* w3T  = (unsigned short*)alloc((size_t)D*D*2);
    unsigned short* agw1T= (unsigned short*)alloc((size_t)2*D*D*2);
    unsigned short* agw2T= (unsigned short*)alloc((size_t)D*D*2);
    unsigned short* agw3T= (unsigned short*)alloc((size_t)D*D*2);
    float* Cp = (float*)alloc((size_t)8*MN*4);   // up to 8 split-K partial slices
    size_t persist = off;

    // chunk: geoPc f32 + h1c bf16 + h2c bf16 + fcb bf16
    size_t chunk_unit = (size_t)NP*(GEO*4 + D*2 + D*2 + D*2);
    int CH = 64;
    while (CH > 1 && persist + (size_t)CH*chunk_unit + 4096 > ws_size) CH >>= 1;
    float*          geoPc = (float*)(wsb + persist);
    unsigned short* h1c   = (unsigned short*)((char*)geoPc + (size_t)CH*NP*GEO*4);
    unsigned short* h2c   = (unsigned short*)((char*)h1c   + (size_t)CH*NP*D*2);
    unsigned short* fcb   = (unsigned short*)((char*)h2c   + (size_t)CH*NP*D*2);

    const float* W1c = pm_w1 + (size_t)2*D*D;   // geo slice of pm_w1

    // 0) all weight transposes + bf16 in one dispatch
    WT7 d;
    d.src[0]=pm_w1;              d.dst[0]=w1aT;  d.kt[0]=16;
    d.src[1]=pm_w1+(size_t)D*D;  d.dst[1]=w1bT;  d.kt[1]=16;
    d.src[2]=pm_w2;              d.dst[2]=w2T;   d.kt[2]=16;
    d.src[3]=pm_w3;              d.dst[3]=w3T;   d.kt[3]=16;
    d.src[4]=ag_w1;              d.dst[4]=agw1T; d.kt[4]=32;
    d.src[5]=ag_w2;              d.dst[5]=agw2T; d.kt[5]=16;
    d.src[6]=ag_w3;              d.dst[6]=agw3T; d.kt[6]=16;
    d.pre[0]=0;
    for (int e = 0; e < 7; ++e) d.pre[e+1] = d.pre[e] + d.kt[e]*16;
    k_wTall<<<d.pre[7], 256, 0, stream>>>(d);

    // 1) U,V = feats @ {w1a, w1b}: split-K MFMA (KZ=4, 2 mats) + reduce
    k_skmm<true><<<dim3(M/16, D/128, 8), 256, 0, stream>>>(
        feats, nullptr, D, 0, w1aT, w1bT, Cp, 4, 256, D);
    k_red<false,false><<<dim3(MN/1024, 1, 2), 256, 0, stream>>>(
        Cp, 4, nullptr, Ub, Vb, MN, D);

    // 2) chunked over (b,i) rows: geo -> h1(bf16) -> h2 -> fet -> topk
    int nchunks = M/CH;
    for (int cchunk = 0; cchunk < nchunks; ++cchunk) {
        int bi0  = cchunk * CH;
        int pofs = bi0 * NP;
        k_geo<<<CH*NP/4, 256, 0, stream>>>(prop, gp_w1, gp_b1, gp_w2, gp_b2, gp_w3, gp_b3, geoPc, pofs);
        k_h1<<<CH*NP/8, 256, 0, stream>>>(geoPc, W1c, pm_b1, Ub, Vb, h1c, pofs);
        dim3 gBig(CH*NP/128, D/128);
        k_mgemm<true ,true><<<gBig, 256, 0, stream>>>(h1c, w2T, pm_b2, h2c, CH*NP, D, D);
        k_mgemm<false,true><<<gBig, 256, 0, stream>>>(h2c, w3T, pm_b3, fcb, CH*NP, D, D);
        k_topk<<<CH*D/256, 256, 0, stream>>>(fcb, red + (size_t)bi0*D);
    }

    // 3) aggregate MLP via split-K MFMA + fused reduce/activation
    // ag1: [feats|red] (K=2048) @ ag_w1, KZ=8
    k_skmm<true><<<dim3(M/16, D/128, 8), 256, 0, stream>>>(
        feats, red, D, D, agw1T, nullptr, Cp, 8, 256, D);
    k_red<true,true><<<dim3(MN/1024, 1, 1), 256, 0, stream>>>(
        Cp, 8, ag_b1, xh1b, nullptr, MN, D);
    // ag2
    k_skmm<false><<<dim3(M/16, D/128, 4), 256, 0, stream>>>(
        xh1b, nullptr, D, 0, agw2T, nullptr, Cp, 4, 256, D);
    k_red<true,true><<<dim3(MN/1024, 1, 1), 256, 0, stream>>>(
        Cp, 4, ag_b2, xh2b, nullptr, MN, D);
    // ag3
    k_skmm<false><<<dim3(M/16, D/128, 4), 256, 0, stream>>>(
        xh2b, nullptr, D, 0, agw3T, nullptr, Cp, 4, 256, D);
    k_red<false,false><<<dim3(MN/1024, 1, 1), 256, 0, stream>>>(
        Cp, 4, ag_b3, xf, nullptr, MN, D);

    // 4) sigmoid heads
    k_final<<<M, 256, 0, stream>>>(xf, subject, obj, cs_w, cs_b, cso_w, cso_b, out);
}

// Round 8
// 666.417 us; speedup vs baseline: 3.9121x; 1.2003x over previous
//
#include <hip/hip_runtime.h>
#include <hip/hip_bf16.h>
#include <math.h>

#define D 1024
#define NP 128
#define BS 2
#define GEO 64
#define TOPKN 18
#define NPAIR (BS*NP*NP)   // 32768

__device__ __forceinline__ float relu_(float x){ return fmaxf(x, 0.f); }
__device__ __forceinline__ unsigned short f2b(float x){
    __hip_bfloat16 h = __float2bfloat16(x);
    return *(unsigned short*)&h;
}
__device__ __forceinline__ float b2f(unsigned short u){
    return __uint_as_float((unsigned)u << 16);
}

typedef short bf16x8 __attribute__((ext_vector_type(8)));
typedef float f32x4  __attribute__((ext_vector_type(4)));

// async global->LDS, 16B per lane. LDS dest must be wave-uniform base + lane*16.
__device__ __forceinline__ void glds16(const unsigned short* g, unsigned short* l){
    __builtin_amdgcn_global_load_lds(
        (const __attribute__((address_space(1))) void*)g,
        (__attribute__((address_space(3))) void*)l,
        16, 0, 0);
}

// ---------------- geo embedding + 3x Linear(64,64) MLP (chunk-local) ----------
__global__ __launch_bounds__(256) void k_geo(
    const float* __restrict__ prop,
    const float* __restrict__ gw1, const float* __restrict__ gb1,
    const float* __restrict__ gw2, const float* __restrict__ gb2,
    const float* __restrict__ gw3, const float* __restrict__ gb3,
    float* __restrict__ geoPc, int pofs)
{
    __shared__ float w[3][GEO*GEO];
    __shared__ float bias[3][GEO];
    int tid = threadIdx.x;
    for (int idx = tid; idx < GEO*GEO; idx += 256) {
        w[0][idx] = gw1[idx]; w[1][idx] = gw2[idx]; w[2][idx] = gw3[idx];
    }
    if (tid < GEO) { bias[0][tid]=gb1[tid]; bias[1][tid]=gb2[tid]; bias[2][tid]=gb3[tid]; }
    __syncthreads();
    int lane = tid & 63;
    int wave = tid >> 6;
    int gwave = blockIdx.x*4 + wave;
    int pair  = pofs + gwave;
    int p = lane >> 4;
    int s = lane & 15;
    int f = s & 7;
    float dm = expf((float)f * (6.907755278982137f/8.0f)); // 1000^(f/8)
    bool is_cos = (s & 8) != 0;
    float scale = 100.f / dm;

    int b  = pair >> 14;
    int ij = pair & 16383;
    int i  = ij >> 7;
    int j  = ij & 127;
    float4 pi = *(const float4*)(prop + (size_t)(b*NP + i)*4);
    float4 pj = *(const float4*)(prop + (size_t)(b*NP + j)*4);
    float wi  = pi.z-pi.x+1.f, hi_ = pi.w-pi.y+1.f;
    float wj  = pj.z-pj.x+1.f, hj  = pj.w-pj.y+1.f;
    float pos;
    if      (p == 0) pos = (0.5f*(pi.x+pi.z) - 0.5f*(pj.x+pj.z)) / wj;
    else if (p == 1) pos = (0.5f*(pi.y+pi.w) - 0.5f*(pj.y+pj.w)) / hj;
    else if (p == 2) pos = wi / wj;
    else             pos = hi_ / hj;
    pos = logf(fmaxf(fabsf(pos), 1e-3f));
    float dv = pos * scale;
    float v = is_cos ? cosf(dv) : sinf(dv);
    #pragma unroll
    for (int layer = 0; layer < 3; ++layer) {
        float acc = bias[layer][lane];
        for (int k = 0; k < GEO; ++k) {
            float vk = __shfl(v, k, 64);
            acc = fmaf(vk, w[layer][k*GEO + lane], acc);
        }
        v = (layer < 2) ? relu_(acc) : acc;
    }
    geoPc[(size_t)gwave*GEO + lane] = v;
}

// ------------- batched weight transpose+bf16: 7 matrices, N=1024 cols -------------
struct WT7 {
    const float* src[7];
    unsigned short* dst[7];
    int kt[7];     // K/64
    int pre[8];    // prefix of tile counts (kt*16)
};
__global__ __launch_bounds__(256) void k_wTall(WT7 d)
{
    __shared__ float tile[64][65];
    int bid = blockIdx.x;
    int e = 0;
    while (e < 6 && bid >= d.pre[e+1]) ++e;
    int local = bid - d.pre[e];
    int bx = local & 15;      // n-tile (N=1024 -> 16 tiles)
    int by = local >> 4;      // k-tile
    int K = d.kt[e] * 64;
    const float* W = d.src[e];
    unsigned short* WT = d.dst[e];
    int t = threadIdx.x;
    int tc = t & 63, tr = t >> 6;
    #pragma unroll
    for (int r = tr; r < 64; r += 4)
        tile[r][tc] = W[(size_t)(by*64 + r)*1024 + bx*64 + tc];
    __syncthreads();
    #pragma unroll
    for (int r = tr; r < 64; r += 4)
        WT[(size_t)(bx*64 + r)*K + by*64 + tc] = f2b(tile[tc][r]);
}

// ---------------- split-K MFMA GEMM for M=256 layers ----------------
template<bool A_F32>
__global__ __launch_bounds__(256) void k_skmm(
    const void* __restrict__ A1v, const void* __restrict__ A2v,
    int K1, int K2,
    const unsigned short* __restrict__ BT0,
    const unsigned short* __restrict__ BT1,
    float* __restrict__ Cp,
    int KZ, int Kc, int N)
{
    __shared__ unsigned short As[16*32];
    __shared__ unsigned short Bs[128*32];
    int t = threadIdx.x;
    int m0 = blockIdx.x * 16;
    int n0 = blockIdx.y * 128;
    int bz = blockIdx.z;
    int kz = bz % KZ;
    int mat = bz / KZ;
    const unsigned short* BT = mat ? BT1 : BT0;
    int K = K1 + K2;
    int M = gridDim.x * 16;
    int w = t >> 6, l = t & 63;
    int lr = l & 15, lq = l >> 4;
    int arow = t >> 3, ak = (t & 7) * 4;
    int arow2 = t >> 2, ak2 = (t & 3) * 8;
    int brow = t >> 1, bk = (t & 1) * 16;
    f32x4 acc0 = {0.f,0.f,0.f,0.f}, acc1 = {0.f,0.f,0.f,0.f};
    for (int i = 0; i < Kc; i += 32) {
        int kg0 = kz*Kc + i;
        __syncthreads();
        if (A_F32) {
            if (t < 128) {
                int kg = kg0 + ak;
                const float* src = (kg < K1)
                    ? (const float*)A1v + (size_t)(m0+arow)*K1 + kg
                    : (const float*)A2v + (size_t)(m0+arow)*K2 + (kg - K1);
                float4 a4 = *(const float4*)src;
                ushort4 u;
                u.x=f2b(a4.x); u.y=f2b(a4.y); u.z=f2b(a4.z); u.w=f2b(a4.w);
                *(ushort4*)(As + arow*32 + ak) = u;
            }
        } else {
            if (t < 64) {
                const unsigned short* src = (const unsigned short*)A1v + (size_t)(m0+arow2)*K1 + kg0 + ak2;
                *(bf16x8*)(As + arow2*32 + ak2) = *(const bf16x8*)src;
            }
        }
        const unsigned short* srcb = BT + (size_t)(n0+brow)*K + kg0 + bk;
        *(bf16x8*)(Bs + brow*32 + bk)     = *(const bf16x8*)srcb;
        *(bf16x8*)(Bs + brow*32 + bk + 8) = *(const bf16x8*)(srcb + 8);
        __syncthreads();
        bf16x8 af = *(const bf16x8*)(As + lr*32 + lq*8);
        bf16x8 b0 = *(const bf16x8*)(Bs + (w*32      + lr)*32 + lq*8);
        bf16x8 b1 = *(const bf16x8*)(Bs + (w*32 + 16 + lr)*32 + lq*8);
        acc0 = __builtin_amdgcn_mfma_f32_16x16x32_bf16(af, b0, acc0, 0, 0, 0);
        acc1 = __builtin_amdgcn_mfma_f32_16x16x32_bf16(af, b1, acc1, 0, 0, 0);
    }
    float* Co = Cp + (size_t)bz*M*N;
    #pragma unroll
    for (int r = 0; r < 4; ++r) {
        int gr = m0 + lq*4 + r;
        Co[(size_t)gr*N + n0 + w*32      + lr] = acc0[r];
        Co[(size_t)gr*N + n0 + w*32 + 16 + lr] = acc1[r];
    }
}

// ---------------- reduce split-K partials: out = act(sum + bias) ----------------
template<bool RELU, bool OUT_BF16>
__global__ __launch_bounds__(256) void k_red(
    const float* __restrict__ Cp, int KZ,
    const float* __restrict__ bias,
    void* __restrict__ out0, void* __restrict__ out1,
    int MN, int N)
{
    int z = blockIdx.z;
    const float* C = Cp + (size_t)z*KZ*MN;
    void* out = z ? out1 : out0;
    int idx = (blockIdx.x*256 + threadIdx.x) * 4;
    f32x4 s = {0.f,0.f,0.f,0.f};
    for (int k = 0; k < KZ; ++k)
        s += *(const f32x4*)(C + (size_t)k*MN + idx);
    if (bias) s += *(const f32x4*)(bias + (idx & (N-1)));
    if (RELU) { s[0]=relu_(s[0]); s[1]=relu_(s[1]); s[2]=relu_(s[2]); s[3]=relu_(s[3]); }
    if (OUT_BF16) {
        ushort4 u; u.x=f2b(s[0]); u.y=f2b(s[1]); u.z=f2b(s[2]); u.w=f2b(s[3]);
        *(ushort4*)((unsigned short*)out + idx) = u;
    } else {
        float4 o; o.x=s[0]; o.y=s[1]; o.z=s[2]; o.w=s[3];
        *(float4*)((float*)out + idx) = o;
    }
}

// ---------------- bf16 MFMA GEMM (m97 structure): C = act(A@B + bias) ----------
template<bool RELU, bool OUT_BF16>
__global__ __launch_bounds__(256) void k_mgemm(
    const unsigned short* __restrict__ A,
    const unsigned short* __restrict__ BT,
    const float* __restrict__ bias,
    void* __restrict__ Cv, int M, int N, int K)
{
    __shared__ unsigned short As[128*32];
    __shared__ unsigned short Bs[128*32];
    int t  = threadIdx.x;
    int m0 = blockIdx.x * 128;
    int n0 = blockIdx.y * 128;
    int w  = t >> 6, l = t & 63;
    int wm = w & 1, wn = w >> 1;
    int lr = l & 15;
    int lq = l >> 4;

    int s0 = w*2, s1 = w*2 + 1;
    int srow = l >> 2;
    int sko  = (l & 3) * 8;
    int rowA0 = s0*16 + srow, rowA1 = s1*16 + srow;
    unsigned short* ldsA0 = As + s0*512 + l*8;
    unsigned short* ldsA1 = As + s1*512 + l*8;
    unsigned short* ldsB0 = Bs + s0*512 + l*8;
    unsigned short* ldsB1 = Bs + s1*512 + l*8;

    f32x4 acc[4][4];
    #pragma unroll
    for (int mi = 0; mi < 4; ++mi)
        #pragma unroll
        for (int ni = 0; ni < 4; ++ni)
            #pragma unroll
            for (int r = 0; r < 4; ++r) acc[mi][ni][r] = 0.f;

    for (int k0 = 0; k0 < K; k0 += 32) {
        glds16(A  + (size_t)(m0 + rowA0)*K + k0 + sko, ldsA0);
        glds16(A  + (size_t)(m0 + rowA1)*K + k0 + sko, ldsA1);
        glds16(BT + (size_t)(n0 + rowA0)*K + k0 + sko, ldsB0);
        glds16(BT + (size_t)(n0 + rowA1)*K + k0 + sko, ldsB1);
        __syncthreads();
        bf16x8 af[4], bf[4];
        #pragma unroll
        for (int mi = 0; mi < 4; ++mi)
            af[mi] = *(const bf16x8*)(As + (wm*64 + mi*16 + lr)*32 + lq*8);
        #pragma unroll
        for (int ni = 0; ni < 4; ++ni)
            bf[ni] = *(const bf16x8*)(Bs + (wn*64 + ni*16 + lr)*32 + lq*8);
        #pragma unroll
        for (int mi = 0; mi < 4; ++mi)
            #pragma unroll
            for (int ni = 0; ni < 4; ++ni)
                acc[mi][ni] = __builtin_amdgcn_mfma_f32_16x16x32_bf16(af[mi], bf[ni], acc[mi][ni], 0, 0, 0);
        __syncthreads();
    }

    #pragma unroll
    for (int mi = 0; mi < 4; ++mi) {
        #pragma unroll
        for (int ni = 0; ni < 4; ++ni) {
            int gc = n0 + wn*64 + ni*16 + lr;
            int gr = m0 + wm*64 + mi*16 + lq*4;
            float bval = bias ? bias[gc] : 0.f;
            #pragma unroll
            for (int r = 0; r < 4; ++r) {
                float v = acc[mi][ni][r] + bval;
                if (RELU) v = relu_(v);
                if (OUT_BF16) ((unsigned short*)Cv)[(size_t)(gr + r)*N + gc] = f2b(v);
                else          ((float*)Cv)[(size_t)(gr + r)*N + gc] = v;
            }
        }
    }
}

// ------- fused fet GEMM + top-18 + sum/8: one block = one bl row-group x 128 ch ----
// A=h2c [M,K], BT=w3T [N,K], bias=pm_b3. Block (bx,by): rows bx*128 (=all j of bl=bx),
// cols by*128. Emits red_out[bx*N + by*128 + c] directly. No fet materialization.
#define TLDS 130   // LDS tile stride (bf16) for the 128x128 fet tile
__global__ __launch_bounds__(256) void k_mgemm_topk(
    const unsigned short* __restrict__ A,
    const unsigned short* __restrict__ BT,
    const float* __restrict__ bias,
    float* __restrict__ red_out,
    int N, int K)
{
    __shared__ unsigned char smem[128*TLDS*2];          // 33280 B, aliased phases
    unsigned short* As = (unsigned short*)smem;         // [128*32] k-loop phase
    unsigned short* Bs = As + 128*32;
    unsigned short* tile = (unsigned short*)smem;       // [128][TLDS] tile phase
    float* lists = (float*)smem;                        // [256][18] merge phase

    int t  = threadIdx.x;
    int m0 = blockIdx.x * 128;
    int n0 = blockIdx.y * 128;
    int w  = t >> 6, l = t & 63;
    int wm = w & 1, wn = w >> 1;
    int lr = l & 15;
    int lq = l >> 4;

    int s0 = w*2, s1 = w*2 + 1;
    int srow = l >> 2;
    int sko  = (l & 3) * 8;
    int rowA0 = s0*16 + srow, rowA1 = s1*16 + srow;
    unsigned short* ldsA0 = As + s0*512 + l*8;
    unsigned short* ldsA1 = As + s1*512 + l*8;
    unsigned short* ldsB0 = Bs + s0*512 + l*8;
    unsigned short* ldsB1 = Bs + s1*512 + l*8;

    f32x4 acc[4][4];
    #pragma unroll
    for (int mi = 0; mi < 4; ++mi)
        #pragma unroll
        for (int ni = 0; ni < 4; ++ni)
            #pragma unroll
            for (int r = 0; r < 4; ++r) acc[mi][ni][r] = 0.f;

    for (int k0 = 0; k0 < K; k0 += 32) {
        glds16(A  + (size_t)(m0 + rowA0)*K + k0 + sko, ldsA0);
        glds16(A  + (size_t)(m0 + rowA1)*K + k0 + sko, ldsA1);
        glds16(BT + (size_t)(n0 + rowA0)*K + k0 + sko, ldsB0);
        glds16(BT + (size_t)(n0 + rowA1)*K + k0 + sko, ldsB1);
        __syncthreads();
        bf16x8 af[4], bf[4];
        #pragma unroll
        for (int mi = 0; mi < 4; ++mi)
            af[mi] = *(const bf16x8*)(As + (wm*64 + mi*16 + lr)*32 + lq*8);
        #pragma unroll
        for (int ni = 0; ni < 4; ++ni)
            bf[ni] = *(const bf16x8*)(Bs + (wn*64 + ni*16 + lr)*32 + lq*8);
        #pragma unroll
        for (int mi = 0; mi < 4; ++mi)
            #pragma unroll
            for (int ni = 0; ni < 4; ++ni)
                acc[mi][ni] = __builtin_amdgcn_mfma_f32_16x16x32_bf16(af[mi], bf[ni], acc[mi][ni], 0, 0, 0);
        __syncthreads();   // all As/Bs reads done -> safe to alias as tile
    }

    // phase 2: fet tile (bias added, bf16) -> LDS. row = j (local), col = channel.
    #pragma unroll
    for (int mi = 0; mi < 4; ++mi) {
        #pragma unroll
        for (int ni = 0; ni < 4; ++ni) {
            int col = wn*64 + ni*16 + lr;
            int row = wm*64 + mi*16 + lq*4;
            float bval = bias[n0 + col];
            #pragma unroll
            for (int r = 0; r < 4; ++r)
                tile[(row + r)*TLDS + col] = f2b(acc[mi][ni][r] + bval);
        }
    }
    __syncthreads();

    // phase 3: per-thread top-18 over 64 j (2 threads per channel)
    int c = t & 127, half = t >> 7;
    float sm[TOPKN];
    #pragma unroll
    for (int q = 0; q < TOPKN; ++q) sm[q] = -INFINITY;
    int jbase = half*64;
    for (int j = 0; j < 64; ++j) {
        float v = b2f(tile[(jbase + j)*TLDS + c]);
        #pragma unroll
        for (int q = 0; q < TOPKN; ++q) {
            float mx = fmaxf(sm[q], v);
            v = fminf(sm[q], v);
            sm[q] = mx;
        }
    }
    __syncthreads();   // all tile reads done -> safe to alias as lists

    #pragma unroll
    for (int q = 0; q < TOPKN; ++q) lists[t*TOPKN + q] = sm[q];
    __syncthreads();

    // phase 4: merge the two sorted desc lists per channel, sum top-18
    if (t < 128) {
        const float* la = lists + t*TOPKN;
        const float* lb = lists + (t + 128)*TOPKN;
        int ia = 0, ib = 0;
        float s = 0.f;
        #pragma unroll
        for (int q = 0; q < TOPKN; ++q) {
            float av = la[ia], bv = lb[ib];
            if (av >= bv) { s += av; ++ia; }
            else          { s += bv; ++ib; }
        }
        red_out[(size_t)blockIdx.x*N + n0 + t] = s * 0.125f;
    }
}

// ---------------- h1 = relu(U[b,j] + V[b,i] + geoPc@W1c + b1) -> bf16 ----------
__global__ __launch_bounds__(256) void k_h1(
    const float* __restrict__ geoPc, const float* __restrict__ W1c,
    const float* __restrict__ b1,
    const float* __restrict__ U, const float* __restrict__ V,
    unsigned short* __restrict__ h1c, int pofs)
{
    __shared__ float g[8][GEO];
    int pl    = blockIdx.x * 8;
    int pbase = pofs + pl;
    int b  = pbase >> 14;
    int ij = pbase & 16383;
    int i  = ij >> 7;
    int j0 = ij & 127;
    int tid = threadIdx.x;
    for (int t = tid; t < 8*GEO; t += 256) ((float*)g)[t] = geoPc[(size_t)pl*GEO + t];
    __syncthreads();
    int c = tid * 4;
    float4 base4 = *(const float4*)(b1 + c);
    float4 vv = *(const float4*)(V + (size_t)(b*NP + i)*D + c);
    base4.x += vv.x; base4.y += vv.y; base4.z += vv.z; base4.w += vv.w;
    float4 acc[8];
    #pragma unroll
    for (int pp = 0; pp < 8; ++pp) {
        float4 uu = *(const float4*)(U + (size_t)(b*NP + j0 + pp)*D + c);
        acc[pp].x = base4.x + uu.x; acc[pp].y = base4.y + uu.y;
        acc[pp].z = base4.z + uu.z; acc[pp].w = base4.w + uu.w;
    }
    for (int k = 0; k < GEO; ++k) {
        float4 w4 = *(const float4*)(W1c + (size_t)k*D + c);
        #pragma unroll
        for (int pp = 0; pp < 8; ++pp) {
            float gk = g[pp][k];
            acc[pp].x = fmaf(gk, w4.x, acc[pp].x);
            acc[pp].y = fmaf(gk, w4.y, acc[pp].y);
            acc[pp].z = fmaf(gk, w4.z, acc[pp].z);
            acc[pp].w = fmaf(gk, w4.w, acc[pp].w);
        }
    }
    #pragma unroll
    for (int pp = 0; pp < 8; ++pp) {
        ushort4 o;
        o.x = f2b(relu_(acc[pp].x)); o.y = f2b(relu_(acc[pp].y));
        o.z = f2b(relu_(acc[pp].z)); o.w = f2b(relu_(acc[pp].w));
        *(ushort4*)(h1c + (size_t)(pl + pp)*D + c) = o;
    }
}

// ---------------- final heads -> sigmoid, f32 out ----------------
__global__ __launch_bounds__(256) void k_final(const float* __restrict__ x,
    const float* __restrict__ subject, const float* __restrict__ obj,
    const float* __restrict__ cs_w, const float* __restrict__ cs_b,
    const float* __restrict__ cso_w, const float* __restrict__ cso_b,
    float* __restrict__ out)
{
    int bi = blockIdx.x;
    int b  = bi >> 7;
    const float* xr = x + (size_t)bi*D;
    const float* sb = subject + (size_t)b*D;
    const float* ob = obj + (size_t)b*D;
    int tid = threadIdx.x;
    float a0 = 0.f, a1 = 0.f;
    for (int k = tid; k < D; k += 256) {
        float xv = xr[k];
        a0 = fmaf(xv, cs_w[k], a0);
        a0 = fmaf(sb[k], cs_w[D+k], a0);
        a1 = fmaf(xv, cso_w[k], a1);
        a1 = fmaf(ob[k], cso_w[D+k], a1);
    }
    __shared__ float r0[256], r1[256];
    r0[tid] = a0; r1[tid] = a1;
    __syncthreads();
    for (int s2 = 128; s2 > 0; s2 >>= 1) {
        if (tid < s2) { r0[tid] += r0[tid+s2]; r1[tid] += r1[tid+s2]; }
        __syncthreads();
    }
    if (tid == 0) {
        out[bi*2+0] = 1.f/(1.f + expf(-(r0[0] + cs_b[0])));
        out[bi*2+1] = 1.f/(1.f + expf(-(r1[0] + cso_b[0])));
    }
}

extern "C" void kernel_launch(void* const* d_in, const int* in_sizes, int n_in,
                              void* d_out, int out_size, void* d_ws, size_t ws_size,
                              hipStream_t stream)
{
    const float* feats   = (const float*)d_in[0];
    const float* subject = (const float*)d_in[1];
    const float* obj     = (const float*)d_in[2];
    const float* prop    = (const float*)d_in[3];
    const float* gp_w1 = (const float*)d_in[4];  const float* gp_b1 = (const float*)d_in[5];
    const float* gp_w2 = (const float*)d_in[6];  const float* gp_b2 = (const float*)d_in[7];
    const float* gp_w3 = (const float*)d_in[8];  const float* gp_b3 = (const float*)d_in[9];
    const float* pm_w1 = (const float*)d_in[10]; const float* pm_b1 = (const float*)d_in[11];
    const float* pm_w2 = (const float*)d_in[12]; const float* pm_b2 = (const float*)d_in[13];
    const float* pm_w3 = (const float*)d_in[14]; const float* pm_b3 = (const float*)d_in[15];
    const float* ag_w1 = (const float*)d_in[16]; const float* ag_b1 = (const float*)d_in[17];
    const float* ag_w2 = (const float*)d_in[18]; const float* ag_b2 = (const float*)d_in[19];
    const float* ag_w3 = (const float*)d_in[20]; const float* ag_b3 = (const float*)d_in[21];
    const float* cs_w  = (const float*)d_in[22]; const float* cs_b  = (const float*)d_in[23];
    const float* cso_w = (const float*)d_in[24]; const float* cso_b = (const float*)d_in[25];
    float* out = (float*)d_out;

    const int M = BS*NP;          // 256
    const int MN = M*D;           // 262144

    // ---- workspace layout (bytes) ----
    char* wsb = (char*)d_ws;
    size_t off = 0;
    auto alloc = [&](size_t bytes) { char* p = wsb + off; off += (bytes + 255) & ~255ull; return p; };
    float* Ub  = (float*)alloc((size_t)MN*4);
    float* Vb  = (float*)alloc((size_t)MN*4);
    float* red = (float*)alloc((size_t)MN*4);
    float* xf  = (float*)alloc((size_t)MN*4);
    unsigned short* xh1b = (unsigned short*)alloc((size_t)MN*2);
    unsigned short* xh2b = (unsigned short*)alloc((size_t)MN*2);
    unsigned short* w1aT = (unsigned short*)alloc((size_t)D*D*2);
    unsigned short* w1bT = (unsigned short*)alloc((size_t)D*D*2);
    unsigned short* w2T  = (unsigned short*)alloc((size_t)D*D*2);
    unsigned short* w3T  = (unsigned short*)alloc((size_t)D*D*2);
    unsigned short* agw1T= (unsigned short*)alloc((size_t)2*D*D*2);
    unsigned short* agw2T= (unsigned short*)alloc((size_t)D*D*2);
    unsigned short* agw3T= (unsigned short*)alloc((size_t)D*D*2);
    float* Cp = (float*)alloc((size_t)8*MN*4);   // up to 8 split-K partial slices
    size_t persist = off;

    // chunk: geoPc f32 + h1c bf16 + h2c bf16  (fet no longer materialized)
    size_t chunk_unit = (size_t)NP*(GEO*4 + D*2 + D*2);
    int CH = 64;
    while (CH > 1 && persist + (size_t)CH*chunk_unit + 4096 > ws_size) CH >>= 1;
    float*          geoPc = (float*)(wsb + persist);
    unsigned short* h1c   = (unsigned short*)((char*)geoPc + (size_t)CH*NP*GEO*4);
    unsigned short* h2c   = (unsigned short*)((char*)h1c   + (size_t)CH*NP*D*2);

    const float* W1c = pm_w1 + (size_t)2*D*D;   // geo slice of pm_w1

    // 0) all weight transposes + bf16 in one dispatch
    WT7 d;
    d.src[0]=pm_w1;              d.dst[0]=w1aT;  d.kt[0]=16;
    d.src[1]=pm_w1+(size_t)D*D;  d.dst[1]=w1bT;  d.kt[1]=16;
    d.src[2]=pm_w2;              d.dst[2]=w2T;   d.kt[2]=16;
    d.src[3]=pm_w3;              d.dst[3]=w3T;   d.kt[3]=16;
    d.src[4]=ag_w1;              d.dst[4]=agw1T; d.kt[4]=32;
    d.src[5]=ag_w2;              d.dst[5]=agw2T; d.kt[5]=16;
    d.src[6]=ag_w3;              d.dst[6]=agw3T; d.kt[6]=16;
    d.pre[0]=0;
    for (int e = 0; e < 7; ++e) d.pre[e+1] = d.pre[e] + d.kt[e]*16;
    k_wTall<<<d.pre[7], 256, 0, stream>>>(d);

    // 1) U,V = feats @ {w1a, w1b}: split-K MFMA (KZ=4, 2 mats) + reduce
    k_skmm<true><<<dim3(M/16, D/128, 8), 256, 0, stream>>>(
        feats, nullptr, D, 0, w1aT, w1bT, Cp, 4, 256, D);
    k_red<false,false><<<dim3(MN/1024, 1, 2), 256, 0, stream>>>(
        Cp, 4, nullptr, Ub, Vb, MN, D);

    // 2) chunked over (b,i) rows: geo -> h1(bf16) -> h2 -> fused fet+topk
    int nchunks = M/CH;
    for (int cchunk = 0; cchunk < nchunks; ++cchunk) {
        int bi0  = cchunk * CH;
        int pofs = bi0 * NP;
        k_geo<<<CH*NP/4, 256, 0, stream>>>(prop, gp_w1, gp_b1, gp_w2, gp_b2, gp_w3, gp_b3, geoPc, pofs);
        k_h1<<<CH*NP/8, 256, 0, stream>>>(geoPc, W1c, pm_b1, Ub, Vb, h1c, pofs);
        dim3 gBig(CH*NP/128, D/128);
        k_mgemm<true,true><<<gBig, 256, 0, stream>>>(h1c, w2T, pm_b2, h2c, CH*NP, D, D);
        k_mgemm_topk<<<dim3(CH, D/128), 256, 0, stream>>>(h2c, w3T, pm_b3,
                                                          red + (size_t)bi0*D, D, D);
    }

    // 3) aggregate MLP via split-K MFMA + fused reduce/activation
    k_skmm<true><<<dim3(M/16, D/128, 8), 256, 0, stream>>>(
        feats, red, D, D, agw1T, nullptr, Cp, 8, 256, D);
    k_red<true,true><<<dim3(MN/1024, 1, 1), 256, 0, stream>>>(
        Cp, 8, ag_b1, xh1b, nullptr, MN, D);
    k_skmm<false><<<dim3(M/16, D/128, 4), 256, 0, stream>>>(
        xh1b, nullptr, D, 0, agw2T, nullptr, Cp, 4, 256, D);
    k_red<true,true><<<dim3(MN/1024, 1, 1), 256, 0, stream>>>(
        Cp, 4, ag_b2, xh2b, nullptr, MN, D);
    k_skmm<false><<<dim3(M/16, D/128, 4), 256, 0, stream>>>(
        xh2b, nullptr, D, 0, agw3T, nullptr, Cp, 4, 256, D);
    k_red<false,false><<<dim3(MN/1024, 1, 1), 256, 0, stream>>>(
        Cp, 4, ag_b3, xf, nullptr, MN, D);

    // 4) sigmoid heads
    k_final<<<M, 256, 0, stream>>>(xf, subject, obj, cs_w, cs_b, cso_w, cso_b, out);
}

// Round 9
// 614.079 us; speedup vs baseline: 4.2455x; 1.0852x over previous
//
#include <hip/hip_runtime.h>
#include <hip/hip_bf16.h>
#include <math.h>

#define D 1024
#define NP 128
#define BS 2
#define GEO 64
#define TOPKN 18
#define NPAIR (BS*NP*NP)   // 32768

__device__ __forceinline__ float relu_(float x){ return fmaxf(x, 0.f); }
__device__ __forceinline__ unsigned short f2b(float x){
    __hip_bfloat16 h = __float2bfloat16(x);
    return *(unsigned short*)&h;
}
__device__ __forceinline__ float b2f(unsigned short u){
    return __uint_as_float((unsigned)u << 16);
}

typedef short bf16x8 __attribute__((ext_vector_type(8)));
typedef float f32x4  __attribute__((ext_vector_type(4)));

// async global->LDS, 16B per lane. LDS dest must be wave-uniform base + lane*16.
__device__ __forceinline__ void glds16(const unsigned short* g, unsigned short* l){
    __builtin_amdgcn_global_load_lds(
        (const __attribute__((address_space(1))) void*)g,
        (__attribute__((address_space(3))) void*)l,
        16, 0, 0);
}

// ---------------- geo embedding + 3x Linear(64,64) MLP (chunk-local, bf16 out) ----
__global__ __launch_bounds__(256) void k_geo(
    const float* __restrict__ prop,
    const float* __restrict__ gw1, const float* __restrict__ gb1,
    const float* __restrict__ gw2, const float* __restrict__ gb2,
    const float* __restrict__ gw3, const float* __restrict__ gb3,
    unsigned short* __restrict__ geoPc, int pofs)
{
    __shared__ float w[3][GEO*GEO];
    __shared__ float bias[3][GEO];
    int tid = threadIdx.x;
    for (int idx = tid; idx < GEO*GEO; idx += 256) {
        w[0][idx] = gw1[idx]; w[1][idx] = gw2[idx]; w[2][idx] = gw3[idx];
    }
    if (tid < GEO) { bias[0][tid]=gb1[tid]; bias[1][tid]=gb2[tid]; bias[2][tid]=gb3[tid]; }
    __syncthreads();
    int lane = tid & 63;
    int wave = tid >> 6;
    int gwave = blockIdx.x*4 + wave;
    int pair  = pofs + gwave;
    int p = lane >> 4;
    int s = lane & 15;
    int f = s & 7;
    float dm = expf((float)f * (6.907755278982137f/8.0f)); // 1000^(f/8)
    bool is_cos = (s & 8) != 0;
    float scale = 100.f / dm;

    int b  = pair >> 14;
    int ij = pair & 16383;
    int i  = ij >> 7;
    int j  = ij & 127;
    float4 pi = *(const float4*)(prop + (size_t)(b*NP + i)*4);
    float4 pj = *(const float4*)(prop + (size_t)(b*NP + j)*4);
    float wi  = pi.z-pi.x+1.f, hi_ = pi.w-pi.y+1.f;
    float wj  = pj.z-pj.x+1.f, hj  = pj.w-pj.y+1.f;
    float pos;
    if      (p == 0) pos = (0.5f*(pi.x+pi.z) - 0.5f*(pj.x+pj.z)) / wj;
    else if (p == 1) pos = (0.5f*(pi.y+pi.w) - 0.5f*(pj.y+pj.w)) / hj;
    else if (p == 2) pos = wi / wj;
    else             pos = hi_ / hj;
    pos = logf(fmaxf(fabsf(pos), 1e-3f));
    float dv = pos * scale;
    float v = is_cos ? cosf(dv) : sinf(dv);
    #pragma unroll
    for (int layer = 0; layer < 3; ++layer) {
        float acc = bias[layer][lane];
        for (int k = 0; k < GEO; ++k) {
            float vk = __shfl(v, k, 64);
            acc = fmaf(vk, w[layer][k*GEO + lane], acc);
        }
        v = (layer < 2) ? relu_(acc) : acc;
    }
    geoPc[(size_t)gwave*GEO + lane] = f2b(v);
}

// ------------- batched weight transpose+bf16: 8 matrices, N=1024 cols -------------
struct WT8 {
    const float* src[8];
    unsigned short* dst[8];
    int kt[8];     // K/64
    int pre[9];    // prefix of tile counts (kt*16)
};
__global__ __launch_bounds__(256) void k_wTall(WT8 d)
{
    __shared__ float tile[64][65];
    int bid = blockIdx.x;
    int e = 0;
    while (e < 7 && bid >= d.pre[e+1]) ++e;
    int local = bid - d.pre[e];
    int bx = local & 15;      // n-tile (N=1024 -> 16 tiles)
    int by = local >> 4;      // k-tile
    int K = d.kt[e] * 64;
    const float* W = d.src[e];
    unsigned short* WT = d.dst[e];
    int t = threadIdx.x;
    int tc = t & 63, tr = t >> 6;
    #pragma unroll
    for (int r = tr; r < 64; r += 4)
        tile[r][tc] = W[(size_t)(by*64 + r)*1024 + bx*64 + tc];
    __syncthreads();
    #pragma unroll
    for (int r = tr; r < 64; r += 4)
        WT[(size_t)(bx*64 + r)*K + by*64 + tc] = f2b(tile[tc][r]);
}

// ---------------- split-K MFMA GEMM for M=256 layers ----------------
template<bool A_F32>
__global__ __launch_bounds__(256) void k_skmm(
    const void* __restrict__ A1v, const void* __restrict__ A2v,
    int K1, int K2,
    const unsigned short* __restrict__ BT0,
    const unsigned short* __restrict__ BT1,
    float* __restrict__ Cp,
    int KZ, int Kc, int N)
{
    __shared__ unsigned short As[16*32];
    __shared__ unsigned short Bs[128*32];
    int t = threadIdx.x;
    int m0 = blockIdx.x * 16;
    int n0 = blockIdx.y * 128;
    int bz = blockIdx.z;
    int kz = bz % KZ;
    int mat = bz / KZ;
    const unsigned short* BT = mat ? BT1 : BT0;
    int K = K1 + K2;
    int M = gridDim.x * 16;
    int w = t >> 6, l = t & 63;
    int lr = l & 15, lq = l >> 4;
    int arow = t >> 3, ak = (t & 7) * 4;
    int arow2 = t >> 2, ak2 = (t & 3) * 8;
    int brow = t >> 1, bk = (t & 1) * 16;
    f32x4 acc0 = {0.f,0.f,0.f,0.f}, acc1 = {0.f,0.f,0.f,0.f};
    for (int i = 0; i < Kc; i += 32) {
        int kg0 = kz*Kc + i;
        __syncthreads();
        if (A_F32) {
            if (t < 128) {
                int kg = kg0 + ak;
                const float* src = (kg < K1)
                    ? (const float*)A1v + (size_t)(m0+arow)*K1 + kg
                    : (const float*)A2v + (size_t)(m0+arow)*K2 + (kg - K1);
                float4 a4 = *(const float4*)src;
                ushort4 u;
                u.x=f2b(a4.x); u.y=f2b(a4.y); u.z=f2b(a4.z); u.w=f2b(a4.w);
                *(ushort4*)(As + arow*32 + ak) = u;
            }
        } else {
            if (t < 64) {
                const unsigned short* src = (const unsigned short*)A1v + (size_t)(m0+arow2)*K1 + kg0 + ak2;
                *(bf16x8*)(As + arow2*32 + ak2) = *(const bf16x8*)src;
            }
        }
        const unsigned short* srcb = BT + (size_t)(n0+brow)*K + kg0 + bk;
        *(bf16x8*)(Bs + brow*32 + bk)     = *(const bf16x8*)srcb;
        *(bf16x8*)(Bs + brow*32 + bk + 8) = *(const bf16x8*)(srcb + 8);
        __syncthreads();
        bf16x8 af = *(const bf16x8*)(As + lr*32 + lq*8);
        bf16x8 b0 = *(const bf16x8*)(Bs + (w*32      + lr)*32 + lq*8);
        bf16x8 b1 = *(const bf16x8*)(Bs + (w*32 + 16 + lr)*32 + lq*8);
        acc0 = __builtin_amdgcn_mfma_f32_16x16x32_bf16(af, b0, acc0, 0, 0, 0);
        acc1 = __builtin_amdgcn_mfma_f32_16x16x32_bf16(af, b1, acc1, 0, 0, 0);
    }
    float* Co = Cp + (size_t)bz*M*N;
    #pragma unroll
    for (int r = 0; r < 4; ++r) {
        int gr = m0 + lq*4 + r;
        Co[(size_t)gr*N + n0 + w*32      + lr] = acc0[r];
        Co[(size_t)gr*N + n0 + w*32 + 16 + lr] = acc1[r];
    }
}

// ---------------- reduce split-K partials: out = act(sum + bias) ----------------
template<bool RELU, bool OUT_BF16>
__global__ __launch_bounds__(256) void k_red(
    const float* __restrict__ Cp, int KZ,
    const float* __restrict__ bias,
    void* __restrict__ out0, void* __restrict__ out1,
    int MN, int N)
{
    int z = blockIdx.z;
    const float* C = Cp + (size_t)z*KZ*MN;
    void* out = z ? out1 : out0;
    int idx = (blockIdx.x*256 + threadIdx.x) * 4;
    f32x4 s = {0.f,0.f,0.f,0.f};
    for (int k = 0; k < KZ; ++k)
        s += *(const f32x4*)(C + (size_t)k*MN + idx);
    if (bias) s += *(const f32x4*)(bias + (idx & (N-1)));
    if (RELU) { s[0]=relu_(s[0]); s[1]=relu_(s[1]); s[2]=relu_(s[2]); s[3]=relu_(s[3]); }
    if (OUT_BF16) {
        ushort4 u; u.x=f2b(s[0]); u.y=f2b(s[1]); u.z=f2b(s[2]); u.w=f2b(s[3]);
        *(ushort4*)((unsigned short*)out + idx) = u;
    } else {
        float4 o; o.x=s[0]; o.y=s[1]; o.z=s[2]; o.w=s[3];
        *(float4*)((float*)out + idx) = o;
    }
}

// ---------------- bf16 MFMA GEMM (m97 structure): C = act(A@B + bias) ----------
template<bool RELU, bool OUT_BF16>
__global__ __launch_bounds__(256) void k_mgemm(
    const unsigned short* __restrict__ A,
    const unsigned short* __restrict__ BT,
    const float* __restrict__ bias,
    void* __restrict__ Cv, int M, int N, int K)
{
    __shared__ unsigned short As[128*32];
    __shared__ unsigned short Bs[128*32];
    int t  = threadIdx.x;
    int m0 = blockIdx.x * 128;
    int n0 = blockIdx.y * 128;
    int w  = t >> 6, l = t & 63;
    int wm = w & 1, wn = w >> 1;
    int lr = l & 15;
    int lq = l >> 4;

    int s0 = w*2, s1 = w*2 + 1;
    int srow = l >> 2;
    int sko  = (l & 3) * 8;
    int rowA0 = s0*16 + srow, rowA1 = s1*16 + srow;
    unsigned short* ldsA0 = As + s0*512 + l*8;
    unsigned short* ldsA1 = As + s1*512 + l*8;
    unsigned short* ldsB0 = Bs + s0*512 + l*8;
    unsigned short* ldsB1 = Bs + s1*512 + l*8;

    f32x4 acc[4][4];
    #pragma unroll
    for (int mi = 0; mi < 4; ++mi)
        #pragma unroll
        for (int ni = 0; ni < 4; ++ni)
            #pragma unroll
            for (int r = 0; r < 4; ++r) acc[mi][ni][r] = 0.f;

    for (int k0 = 0; k0 < K; k0 += 32) {
        glds16(A  + (size_t)(m0 + rowA0)*K + k0 + sko, ldsA0);
        glds16(A  + (size_t)(m0 + rowA1)*K + k0 + sko, ldsA1);
        glds16(BT + (size_t)(n0 + rowA0)*K + k0 + sko, ldsB0);
        glds16(BT + (size_t)(n0 + rowA1)*K + k0 + sko, ldsB1);
        __syncthreads();
        bf16x8 af[4], bf[4];
        #pragma unroll
        for (int mi = 0; mi < 4; ++mi)
            af[mi] = *(const bf16x8*)(As + (wm*64 + mi*16 + lr)*32 + lq*8);
        #pragma unroll
        for (int ni = 0; ni < 4; ++ni)
            bf[ni] = *(const bf16x8*)(Bs + (wn*64 + ni*16 + lr)*32 + lq*8);
        #pragma unroll
        for (int mi = 0; mi < 4; ++mi)
            #pragma unroll
            for (int ni = 0; ni < 4; ++ni)
                acc[mi][ni] = __builtin_amdgcn_mfma_f32_16x16x32_bf16(af[mi], bf[ni], acc[mi][ni], 0, 0, 0);
        __syncthreads();
    }

    #pragma unroll
    for (int mi = 0; mi < 4; ++mi) {
        #pragma unroll
        for (int ni = 0; ni < 4; ++ni) {
            int gc = n0 + wn*64 + ni*16 + lr;
            int gr = m0 + wm*64 + mi*16 + lq*4;
            float bval = bias ? bias[gc] : 0.f;
            #pragma unroll
            for (int r = 0; r < 4; ++r) {
                float v = acc[mi][ni][r] + bval;
                if (RELU) v = relu_(v);
                if (OUT_BF16) ((unsigned short*)Cv)[(size_t)(gr + r)*N + gc] = f2b(v);
                else          ((float*)Cv)[(size_t)(gr + r)*N + gc] = v;
            }
        }
    }
}

// -------- h1 via MFMA: h1 = relu(geo@W1c + U[b,j] + V[b,i] + b1) -> bf16 ----------
// A = geoPc bf16 [CH*NP, 64] chunk-local; BT = w1cT bf16 [D, 64].
__global__ __launch_bounds__(256) void k_h1m(
    const unsigned short* __restrict__ A,
    const unsigned short* __restrict__ BT,
    const float* __restrict__ b1,
    const float* __restrict__ U, const float* __restrict__ V,
    unsigned short* __restrict__ h1c, int pofs)
{
    __shared__ unsigned short As[128*32];
    __shared__ unsigned short Bs[128*32];
    const int K = GEO;   // 64
    int t  = threadIdx.x;
    int m0 = blockIdx.x * 128;
    int n0 = blockIdx.y * 128;
    int w  = t >> 6, l = t & 63;
    int wm = w & 1, wn = w >> 1;
    int lr = l & 15;
    int lq = l >> 4;

    int s0 = w*2, s1 = w*2 + 1;
    int srow = l >> 2;
    int sko  = (l & 3) * 8;
    int rowA0 = s0*16 + srow, rowA1 = s1*16 + srow;
    unsigned short* ldsA0 = As + s0*512 + l*8;
    unsigned short* ldsA1 = As + s1*512 + l*8;
    unsigned short* ldsB0 = Bs + s0*512 + l*8;
    unsigned short* ldsB1 = Bs + s1*512 + l*8;

    f32x4 acc[4][4];
    #pragma unroll
    for (int mi = 0; mi < 4; ++mi)
        #pragma unroll
        for (int ni = 0; ni < 4; ++ni)
            #pragma unroll
            for (int r = 0; r < 4; ++r) acc[mi][ni][r] = 0.f;

    for (int k0 = 0; k0 < K; k0 += 32) {
        glds16(A  + (size_t)(m0 + rowA0)*K + k0 + sko, ldsA0);
        glds16(A  + (size_t)(m0 + rowA1)*K + k0 + sko, ldsA1);
        glds16(BT + (size_t)(n0 + rowA0)*K + k0 + sko, ldsB0);
        glds16(BT + (size_t)(n0 + rowA1)*K + k0 + sko, ldsB1);
        __syncthreads();
        bf16x8 af[4], bf[4];
        #pragma unroll
        for (int mi = 0; mi < 4; ++mi)
            af[mi] = *(const bf16x8*)(As + (wm*64 + mi*16 + lr)*32 + lq*8);
        #pragma unroll
        for (int ni = 0; ni < 4; ++ni)
            bf[ni] = *(const bf16x8*)(Bs + (wn*64 + ni*16 + lr)*32 + lq*8);
        #pragma unroll
        for (int mi = 0; mi < 4; ++mi)
            #pragma unroll
            for (int ni = 0; ni < 4; ++ni)
                acc[mi][ni] = __builtin_amdgcn_mfma_f32_16x16x32_bf16(af[mi], bf[ni], acc[mi][ni], 0, 0, 0);
        __syncthreads();
    }

    // epilogue: rows of this block are j = 0..127 (p0 multiple of 128), i constant
    int p0 = pofs + m0;
    int bi = p0 >> 7;            // b*NP + i
    int b  = bi >> 7;
    const float* Ubase = U + (size_t)b*NP*D;
    const float* Vrow  = V + (size_t)bi*D;
    #pragma unroll
    for (int ni = 0; ni < 4; ++ni) {
        int gc = n0 + wn*64 + ni*16 + lr;
        float add = Vrow[gc] + b1[gc];
        #pragma unroll
        for (int mi = 0; mi < 4; ++mi) {
            int row = wm*64 + mi*16 + lq*4;
            #pragma unroll
            for (int r = 0; r < 4; ++r) {
                float u = Ubase[(size_t)(row + r)*D + gc];
                float val = acc[mi][ni][r] + u + add;
                h1c[(size_t)(m0 + row + r)*D + gc] = f2b(relu_(val));
            }
        }
    }
}

// ------- fused fet GEMM + top-18 + sum/8 (512 threads) --------------------------
// GEMM by t<256 (same m97 structure); topk: 4 threads/channel x 32 j, 2-level merge.
#define TLDS 130
__global__ __launch_bounds__(512) void k_mgemm_topk(
    const unsigned short* __restrict__ A,
    const unsigned short* __restrict__ BT,
    const float* __restrict__ bias,
    float* __restrict__ red_out,
    int N, int K)
{
    __shared__ unsigned char smem[128*TLDS*2 + 256*TOPKN*2]; // 33280 + 9216
    unsigned short* As   = (unsigned short*)smem;            // k-loop phase
    unsigned short* Bs   = As + 128*32;
    unsigned short* tile = (unsigned short*)smem;            // tile phase (alias)
    unsigned short* L1   = (unsigned short*)smem;            // level-1 lists (alias, after tile dead)
    unsigned short* L2   = (unsigned short*)(smem + 128*TLDS*2);

    int t  = threadIdx.x;
    int m0 = blockIdx.x * 128;
    int n0 = blockIdx.y * 128;
    int w  = t >> 6, l = t & 63;
    int wm = w & 1, wn = w >> 1;
    int lr = l & 15;
    int lq = l >> 4;

    int s0 = w*2, s1 = w*2 + 1;
    int sko  = (l & 3) * 8;
    int srow = l >> 2;
    int rowA0 = s0*16 + srow, rowA1 = s1*16 + srow;
    unsigned short* ldsA0 = As + s0*512 + l*8;
    unsigned short* ldsA1 = As + s1*512 + l*8;
    unsigned short* ldsB0 = Bs + s0*512 + l*8;
    unsigned short* ldsB1 = Bs + s1*512 + l*8;

    f32x4 acc[4][4];
    #pragma unroll
    for (int mi = 0; mi < 4; ++mi)
        #pragma unroll
        for (int ni = 0; ni < 4; ++ni)
            #pragma unroll
            for (int r = 0; r < 4; ++r) acc[mi][ni][r] = 0.f;

    for (int k0 = 0; k0 < K; k0 += 32) {
        if (t < 256) {
            glds16(A  + (size_t)(m0 + rowA0)*K + k0 + sko, ldsA0);
            glds16(A  + (size_t)(m0 + rowA1)*K + k0 + sko, ldsA1);
            glds16(BT + (size_t)(n0 + rowA0)*K + k0 + sko, ldsB0);
            glds16(BT + (size_t)(n0 + rowA1)*K + k0 + sko, ldsB1);
        }
        __syncthreads();
        if (t < 256) {
            bf16x8 af[4], bf[4];
            #pragma unroll
            for (int mi = 0; mi < 4; ++mi)
                af[mi] = *(const bf16x8*)(As + (wm*64 + mi*16 + lr)*32 + lq*8);
            #pragma unroll
            for (int ni = 0; ni < 4; ++ni)
                bf[ni] = *(const bf16x8*)(Bs + (wn*64 + ni*16 + lr)*32 + lq*8);
            #pragma unroll
            for (int mi = 0; mi < 4; ++mi)
                #pragma unroll
                for (int ni = 0; ni < 4; ++ni)
                    acc[mi][ni] = __builtin_amdgcn_mfma_f32_16x16x32_bf16(af[mi], bf[ni], acc[mi][ni], 0, 0, 0);
        }
        __syncthreads();
    }

    // phase 2: fet tile (bias added, bf16) -> LDS. row = j, col = channel.
    if (t < 256) {
        #pragma unroll
        for (int mi = 0; mi < 4; ++mi) {
            #pragma unroll
            for (int ni = 0; ni < 4; ++ni) {
                int col = wn*64 + ni*16 + lr;
                int row = wm*64 + mi*16 + lq*4;
                float bval = bias[n0 + col];
                #pragma unroll
                for (int r = 0; r < 4; ++r)
                    tile[(row + r)*TLDS + col] = f2b(acc[mi][ni][r] + bval);
            }
        }
    }
    __syncthreads();

    // phase 3: 4 threads/channel, top-18 over 32 j each
    int c = t & 127, q = t >> 7;
    float sm[TOPKN];
    #pragma unroll
    for (int x = 0; x < TOPKN; ++x) sm[x] = -INFINITY;
    int jbase = q*32;
    for (int j = 0; j < 32; ++j) {
        float v = b2f(tile[(jbase + j)*TLDS + c]);
        #pragma unroll
        for (int x = 0; x < TOPKN; ++x) {
            float mx = fmaxf(sm[x], v);
            v = fminf(sm[x], v);
            sm[x] = mx;
        }
    }
    __syncthreads();   // tile dead -> alias as L1
    {
        unsigned short* my = L1 + (size_t)t*TOPKN;
        #pragma unroll
        for (int x = 0; x < TOPKN; ++x) my[x] = f2b(sm[x]);
    }
    __syncthreads();

    // phase 4: t<256 merges L1 pairs (q=2h,2h+1) -> L2
    if (t < 256) {
        int h = t >> 7;
        const unsigned short* la = L1 + (size_t)((2*h)*128 + c)*TOPKN;
        const unsigned short* lb = L1 + (size_t)((2*h+1)*128 + c)*TOPKN;
        unsigned short* dst = L2 + (size_t)(h*128 + c)*TOPKN;
        int ia = 0, ib = 0;
        float av = b2f(la[0]), bv = b2f(lb[0]);
        #pragma unroll
        for (int x = 0; x < TOPKN; ++x) {
            bool ta = (av >= bv);
            dst[x] = f2b(ta ? av : bv);
            if (ta) { ++ia; av = (ia < TOPKN) ? b2f(la[ia]) : -INFINITY; }
            else    { ++ib; bv = (ib < TOPKN) ? b2f(lb[ib]) : -INFINITY; }
        }
    }
    __syncthreads();

    // phase 5: t<128 merges L2 pair, sum top-18
    if (t < 128) {
        const unsigned short* la = L2 + (size_t)t*TOPKN;
        const unsigned short* lb = L2 + (size_t)(128 + t)*TOPKN;
        int ia = 0, ib = 0;
        float av = b2f(la[0]), bv = b2f(lb[0]);
        float s = 0.f;
        #pragma unroll
        for (int x = 0; x < TOPKN; ++x) {
            bool ta = (av >= bv);
            s += ta ? av : bv;
            if (ta) { ++ia; av = (ia < TOPKN) ? b2f(la[ia]) : -INFINITY; }
            else    { ++ib; bv = (ib < TOPKN) ? b2f(lb[ib]) : -INFINITY; }
        }
        red_out[(size_t)blockIdx.x*N + n0 + t] = s * 0.125f;
    }
}

// ---------------- final heads -> sigmoid, f32 out ----------------
__global__ __launch_bounds__(256) void k_final(const float* __restrict__ x,
    const float* __restrict__ subject, const float* __restrict__ obj,
    const float* __restrict__ cs_w, const float* __restrict__ cs_b,
    const float* __restrict__ cso_w, const float* __restrict__ cso_b,
    float* __restrict__ out)
{
    int bi = blockIdx.x;
    int b  = bi >> 7;
    const float* xr = x + (size_t)bi*D;
    const float* sb = subject + (size_t)b*D;
    const float* ob = obj + (size_t)b*D;
    int tid = threadIdx.x;
    float a0 = 0.f, a1 = 0.f;
    for (int k = tid; k < D; k += 256) {
        float xv = xr[k];
        a0 = fmaf(xv, cs_w[k], a0);
        a0 = fmaf(sb[k], cs_w[D+k], a0);
        a1 = fmaf(xv, cso_w[k], a1);
        a1 = fmaf(ob[k], cso_w[D+k], a1);
    }
    __shared__ float r0[256], r1[256];
    r0[tid] = a0; r1[tid] = a1;
    __syncthreads();
    for (int s2 = 128; s2 > 0; s2 >>= 1) {
        if (tid < s2) { r0[tid] += r0[tid+s2]; r1[tid] += r1[tid+s2]; }
        __syncthreads();
    }
    if (tid == 0) {
        out[bi*2+0] = 1.f/(1.f + expf(-(r0[0] + cs_b[0])));
        out[bi*2+1] = 1.f/(1.f + expf(-(r1[0] + cso_b[0])));
    }
}

extern "C" void kernel_launch(void* const* d_in, const int* in_sizes, int n_in,
                              void* d_out, int out_size, void* d_ws, size_t ws_size,
                              hipStream_t stream)
{
    const float* feats   = (const float*)d_in[0];
    const float* subject = (const float*)d_in[1];
    const float* obj     = (const float*)d_in[2];
    const float* prop    = (const float*)d_in[3];
    const float* gp_w1 = (const float*)d_in[4];  const float* gp_b1 = (const float*)d_in[5];
    const float* gp_w2 = (const float*)d_in[6];  const float* gp_b2 = (const float*)d_in[7];
    const float* gp_w3 = (const float*)d_in[8];  const float* gp_b3 = (const float*)d_in[9];
    const float* pm_w1 = (const float*)d_in[10]; const float* pm_b1 = (const float*)d_in[11];
    const float* pm_w2 = (const float*)d_in[12]; const float* pm_b2 = (const float*)d_in[13];
    const float* pm_w3 = (const float*)d_in[14]; const float* pm_b3 = (const float*)d_in[15];
    const float* ag_w1 = (const float*)d_in[16]; const float* ag_b1 = (const float*)d_in[17];
    const float* ag_w2 = (const float*)d_in[18]; const float* ag_b2 = (const float*)d_in[19];
    const float* ag_w3 = (const float*)d_in[20]; const float* ag_b3 = (const float*)d_in[21];
    const float* cs_w  = (const float*)d_in[22]; const float* cs_b  = (const float*)d_in[23];
    const float* cso_w = (const float*)d_in[24]; const float* cso_b = (const float*)d_in[25];
    float* out = (float*)d_out;

    const int M = BS*NP;          // 256
    const int MN = M*D;           // 262144

    // ---- workspace layout (bytes) ----
    char* wsb = (char*)d_ws;
    size_t off = 0;
    auto alloc = [&](size_t bytes) { char* p = wsb + off; off += (bytes + 255) & ~255ull; return p; };
    float* Ub  = (float*)alloc((size_t)MN*4);
    float* Vb  = (float*)alloc((size_t)MN*4);
    float* red = (float*)alloc((size_t)MN*4);
    float* xf  = (float*)alloc((size_t)MN*4);
    unsigned short* xh1b = (unsigned short*)alloc((size_t)MN*2);
    unsigned short* xh2b = (unsigned short*)alloc((size_t)MN*2);
    unsigned short* w1aT = (unsigned short*)alloc((size_t)D*D*2);
    unsigned short* w1bT = (unsigned short*)alloc((size_t)D*D*2);
    unsigned short* w1cT = (unsigned short*)alloc((size_t)D*GEO*2);
    unsigned short* w2T  = (unsigned short*)alloc((size_t)D*D*2);
    unsigned short* w3T  = (unsigned short*)alloc((size_t)D*D*2);
    unsigned short* agw1T= (unsigned short*)alloc((size_t)2*D*D*2);
    unsigned short* agw2T= (unsigned short*)alloc((size_t)D*D*2);
    unsigned short* agw3T= (unsigned short*)alloc((size_t)D*D*2);
    float* Cp = (float*)alloc((size_t)8*MN*4);   // up to 8 split-K partial slices
    size_t persist = off;

    // chunk: geoPc bf16 + h1c bf16 + h2c bf16
    size_t chunk_unit = (size_t)NP*(GEO*2 + D*2 + D*2);
    int CH = 64;
    while (CH > 1 && persist + (size_t)CH*chunk_unit + 4096 > ws_size) CH >>= 1;
    unsigned short* geoPc = (unsigned short*)(wsb + persist);
    unsigned short* h1c   = geoPc + (size_t)CH*NP*GEO;
    unsigned short* h2c   = h1c   + (size_t)CH*NP*D;

    // 0) all weight transposes + bf16 in one dispatch (incl. W1c geo slice)
    WT8 d;
    d.src[0]=pm_w1;                d.dst[0]=w1aT;  d.kt[0]=16;
    d.src[1]=pm_w1+(size_t)D*D;    d.dst[1]=w1bT;  d.kt[1]=16;
    d.src[2]=pm_w1+(size_t)2*D*D;  d.dst[2]=w1cT;  d.kt[2]=1;
    d.src[3]=pm_w2;                d.dst[3]=w2T;   d.kt[3]=16;
    d.src[4]=pm_w3;                d.dst[4]=w3T;   d.kt[4]=16;
    d.src[5]=ag_w1;                d.dst[5]=agw1T; d.kt[5]=32;
    d.src[6]=ag_w2;                d.dst[6]=agw2T; d.kt[6]=16;
    d.src[7]=ag_w3;                d.dst[7]=agw3T; d.kt[7]=16;
    d.pre[0]=0;
    for (int e = 0; e < 8; ++e) d.pre[e+1] = d.pre[e] + d.kt[e]*16;
    k_wTall<<<d.pre[8], 256, 0, stream>>>(d);

    // 1) U,V = feats @ {w1a, w1b}: split-K MFMA (KZ=4, 2 mats) + reduce
    k_skmm<true><<<dim3(M/16, D/128, 8), 256, 0, stream>>>(
        feats, nullptr, D, 0, w1aT, w1bT, Cp, 4, 256, D);
    k_red<false,false><<<dim3(MN/1024, 1, 2), 256, 0, stream>>>(
        Cp, 4, nullptr, Ub, Vb, MN, D);

    // 2) chunked over (b,i) rows: geo(bf16) -> h1(MFMA) -> h2 -> fused fet+topk
    int nchunks = M/CH;
    for (int cchunk = 0; cchunk < nchunks; ++cchunk) {
        int bi0  = cchunk * CH;
        int pofs = bi0 * NP;
        k_geo<<<CH*NP/4, 256, 0, stream>>>(prop, gp_w1, gp_b1, gp_w2, gp_b2, gp_w3, gp_b3, geoPc, pofs);
        dim3 gBig(CH*NP/128, D/128);
        k_h1m<<<gBig, 256, 0, stream>>>(geoPc, w1cT, pm_b1, Ub, Vb, h1c, pofs);
        k_mgemm<true,true><<<gBig, 256, 0, stream>>>(h1c, w2T, pm_b2, h2c, CH*NP, D, D);
        k_mgemm_topk<<<dim3(CH, D/128), 512, 0, stream>>>(h2c, w3T, pm_b3,
                                                          red + (size_t)bi0*D, D, D);
    }

    // 3) aggregate MLP via split-K MFMA + fused reduce/activation
    k_skmm<true><<<dim3(M/16, D/128, 8), 256, 0, stream>>>(
        feats, red, D, D, agw1T, nullptr, Cp, 8, 256, D);
    k_red<true,true><<<dim3(MN/1024, 1, 1), 256, 0, stream>>>(
        Cp, 8, ag_b1, xh1b, nullptr, MN, D);
    k_skmm<false><<<dim3(M/16, D/128, 4), 256, 0, stream>>>(
        xh1b, nullptr, D, 0, agw2T, nullptr, Cp, 4, 256, D);
    k_red<true,true><<<dim3(MN/1024, 1, 1), 256, 0, stream>>>(
        Cp, 4, ag_b2, xh2b, nullptr, MN, D);
    k_skmm<false><<<dim3(M/16, D/128, 4), 256, 0, stream>>>(
        xh2b, nullptr, D, 0, agw3T, nullptr, Cp, 4, 256, D);
    k_red<false,false><<<dim3(MN/1024, 1, 1), 256, 0, stream>>>(
        Cp, 4, ag_b3, xf, nullptr, MN, D);

    // 4) sigmoid heads
    k_final<<<M, 256, 0, stream>>>(xf, subject, obj, cs_w, cs_b, cso_w, cso_b, out);
}

// Round 10
// 569.300 us; speedup vs baseline: 4.5795x; 1.0787x over previous
//
#include <hip/hip_runtime.h>
#include <hip/hip_bf16.h>
#include <math.h>

#define D 1024
#define NP 128
#define BS 2
#define GEO 64
#define TOPKN 18
#define NPAIR (BS*NP*NP)   // 32768

__device__ __forceinline__ float relu_(float x){ return fmaxf(x, 0.f); }
__device__ __forceinline__ unsigned short f2b(float x){
    __hip_bfloat16 h = __float2bfloat16(x);
    return *(unsigned short*)&h;
}
__device__ __forceinline__ float b2f(unsigned short u){
    return __uint_as_float((unsigned)u << 16);
}

typedef short bf16x8 __attribute__((ext_vector_type(8)));
typedef float f32x4  __attribute__((ext_vector_type(4)));

// async global->LDS, 16B per lane. LDS dest must be wave-uniform base + lane*16.
__device__ __forceinline__ void glds16(const unsigned short* g, unsigned short* l){
    __builtin_amdgcn_global_load_lds(
        (const __attribute__((address_space(1))) void*)g,
        (__attribute__((address_space(3))) void*)l,
        16, 0, 0);
}

// ---------------- geo embedding + 3x Linear(64,64) MLP (chunk-local, bf16 out) ----
__global__ __launch_bounds__(256) void k_geo(
    const float* __restrict__ prop,
    const float* __restrict__ gw1, const float* __restrict__ gb1,
    const float* __restrict__ gw2, const float* __restrict__ gb2,
    const float* __restrict__ gw3, const float* __restrict__ gb3,
    unsigned short* __restrict__ geoPc, int pofs)
{
    __shared__ float w[3][GEO*GEO];
    __shared__ float bias[3][GEO];
    int tid = threadIdx.x;
    for (int idx = tid; idx < GEO*GEO; idx += 256) {
        w[0][idx] = gw1[idx]; w[1][idx] = gw2[idx]; w[2][idx] = gw3[idx];
    }
    if (tid < GEO) { bias[0][tid]=gb1[tid]; bias[1][tid]=gb2[tid]; bias[2][tid]=gb3[tid]; }
    __syncthreads();
    int lane = tid & 63;
    int wave = tid >> 6;
    int gwave = blockIdx.x*4 + wave;
    int pair  = pofs + gwave;
    int p = lane >> 4;
    int s = lane & 15;
    int f = s & 7;
    float dm = expf((float)f * (6.907755278982137f/8.0f)); // 1000^(f/8)
    bool is_cos = (s & 8) != 0;
    float scale = 100.f / dm;

    int b  = pair >> 14;
    int ij = pair & 16383;
    int i  = ij >> 7;
    int j  = ij & 127;
    float4 pi = *(const float4*)(prop + (size_t)(b*NP + i)*4);
    float4 pj = *(const float4*)(prop + (size_t)(b*NP + j)*4);
    float wi  = pi.z-pi.x+1.f, hi_ = pi.w-pi.y+1.f;
    float wj  = pj.z-pj.x+1.f, hj  = pj.w-pj.y+1.f;
    float pos;
    if      (p == 0) pos = (0.5f*(pi.x+pi.z) - 0.5f*(pj.x+pj.z)) / wj;
    else if (p == 1) pos = (0.5f*(pi.y+pi.w) - 0.5f*(pj.y+pj.w)) / hj;
    else if (p == 2) pos = wi / wj;
    else             pos = hi_ / hj;
    pos = logf(fmaxf(fabsf(pos), 1e-3f));
    float dv = pos * scale;
    float v = is_cos ? cosf(dv) : sinf(dv);
    #pragma unroll
    for (int layer = 0; layer < 3; ++layer) {
        float acc = bias[layer][lane];
        for (int k = 0; k < GEO; ++k) {
            float vk = __shfl(v, k, 64);
            acc = fmaf(vk, w[layer][k*GEO + lane], acc);
        }
        v = (layer < 2) ? relu_(acc) : acc;
    }
    geoPc[(size_t)gwave*GEO + lane] = f2b(v);
}

// ------------- batched weight transpose+bf16: 8 matrices, N=1024 cols -------------
struct WT8 {
    const float* src[8];
    unsigned short* dst[8];
    int kt[8];     // K/64
    int pre[9];    // prefix of tile counts (kt*16)
};
__global__ __launch_bounds__(256) void k_wTall(WT8 d)
{
    __shared__ float tile[64][65];
    int bid = blockIdx.x;
    int e = 0;
    while (e < 7 && bid >= d.pre[e+1]) ++e;
    int local = bid - d.pre[e];
    int bx = local & 15;      // n-tile (N=1024 -> 16 tiles)
    int by = local >> 4;      // k-tile
    int K = d.kt[e] * 64;
    const float* W = d.src[e];
    unsigned short* WT = d.dst[e];
    int t = threadIdx.x;
    int tc = t & 63, tr = t >> 6;
    #pragma unroll
    for (int r = tr; r < 64; r += 4)
        tile[r][tc] = W[(size_t)(by*64 + r)*1024 + bx*64 + tc];
    __syncthreads();
    #pragma unroll
    for (int r = tr; r < 64; r += 4)
        WT[(size_t)(bx*64 + r)*K + by*64 + tc] = f2b(tile[tc][r]);
}

// ---------------- split-K MFMA GEMM for M=256 layers ----------------
template<bool A_F32>
__global__ __launch_bounds__(256) void k_skmm(
    const void* __restrict__ A1v, const void* __restrict__ A2v,
    int K1, int K2,
    const unsigned short* __restrict__ BT0,
    const unsigned short* __restrict__ BT1,
    float* __restrict__ Cp,
    int KZ, int Kc, int N)
{
    __shared__ unsigned short As[16*32];
    __shared__ unsigned short Bs[128*32];
    int t = threadIdx.x;
    int m0 = blockIdx.x * 16;
    int n0 = blockIdx.y * 128;
    int bz = blockIdx.z;
    int kz = bz % KZ;
    int mat = bz / KZ;
    const unsigned short* BT = mat ? BT1 : BT0;
    int K = K1 + K2;
    int M = gridDim.x * 16;
    int w = t >> 6, l = t & 63;
    int lr = l & 15, lq = l >> 4;
    int arow = t >> 3, ak = (t & 7) * 4;
    int arow2 = t >> 2, ak2 = (t & 3) * 8;
    int brow = t >> 1, bk = (t & 1) * 16;
    f32x4 acc0 = {0.f,0.f,0.f,0.f}, acc1 = {0.f,0.f,0.f,0.f};
    for (int i = 0; i < Kc; i += 32) {
        int kg0 = kz*Kc + i;
        __syncthreads();
        if (A_F32) {
            if (t < 128) {
                int kg = kg0 + ak;
                const float* src = (kg < K1)
                    ? (const float*)A1v + (size_t)(m0+arow)*K1 + kg
                    : (const float*)A2v + (size_t)(m0+arow)*K2 + (kg - K1);
                float4 a4 = *(const float4*)src;
                ushort4 u;
                u.x=f2b(a4.x); u.y=f2b(a4.y); u.z=f2b(a4.z); u.w=f2b(a4.w);
                *(ushort4*)(As + arow*32 + ak) = u;
            }
        } else {
            if (t < 64) {
                const unsigned short* src = (const unsigned short*)A1v + (size_t)(m0+arow2)*K1 + kg0 + ak2;
                *(bf16x8*)(As + arow2*32 + ak2) = *(const bf16x8*)src;
            }
        }
        const unsigned short* srcb = BT + (size_t)(n0+brow)*K + kg0 + bk;
        *(bf16x8*)(Bs + brow*32 + bk)     = *(const bf16x8*)srcb;
        *(bf16x8*)(Bs + brow*32 + bk + 8) = *(const bf16x8*)(srcb + 8);
        __syncthreads();
        bf16x8 af = *(const bf16x8*)(As + lr*32 + lq*8);
        bf16x8 b0 = *(const bf16x8*)(Bs + (w*32      + lr)*32 + lq*8);
        bf16x8 b1 = *(const bf16x8*)(Bs + (w*32 + 16 + lr)*32 + lq*8);
        acc0 = __builtin_amdgcn_mfma_f32_16x16x32_bf16(af, b0, acc0, 0, 0, 0);
        acc1 = __builtin_amdgcn_mfma_f32_16x16x32_bf16(af, b1, acc1, 0, 0, 0);
    }
    float* Co = Cp + (size_t)bz*M*N;
    #pragma unroll
    for (int r = 0; r < 4; ++r) {
        int gr = m0 + lq*4 + r;
        Co[(size_t)gr*N + n0 + w*32      + lr] = acc0[r];
        Co[(size_t)gr*N + n0 + w*32 + 16 + lr] = acc1[r];
    }
}

// ---------------- reduce split-K partials: out = act(sum + bias) ----------------
template<bool RELU, bool OUT_BF16>
__global__ __launch_bounds__(256) void k_red(
    const float* __restrict__ Cp, int KZ,
    const float* __restrict__ bias,
    void* __restrict__ out0, void* __restrict__ out1,
    int MN, int N)
{
    int z = blockIdx.z;
    const float* C = Cp + (size_t)z*KZ*MN;
    void* out = z ? out1 : out0;
    int idx = (blockIdx.x*256 + threadIdx.x) * 4;
    f32x4 s = {0.f,0.f,0.f,0.f};
    for (int k = 0; k < KZ; ++k)
        s += *(const f32x4*)(C + (size_t)k*MN + idx);
    if (bias) s += *(const f32x4*)(bias + (idx & (N-1)));
    if (RELU) { s[0]=relu_(s[0]); s[1]=relu_(s[1]); s[2]=relu_(s[2]); s[3]=relu_(s[3]); }
    if (OUT_BF16) {
        ushort4 u; u.x=f2b(s[0]); u.y=f2b(s[1]); u.z=f2b(s[2]); u.w=f2b(s[3]);
        *(ushort4*)((unsigned short*)out + idx) = u;
    } else {
        float4 o; o.x=s[0]; o.y=s[1]; o.z=s[2]; o.w=s[3];
        *(float4*)((float*)out + idx) = o;
    }
}

// ---------------- bf16 MFMA GEMM (m97 structure): C = act(A@B + bias) ----------
template<bool RELU, bool OUT_BF16>
__global__ __launch_bounds__(256) void k_mgemm(
    const unsigned short* __restrict__ A,
    const unsigned short* __restrict__ BT,
    const float* __restrict__ bias,
    void* __restrict__ Cv, int M, int N, int K)
{
    __shared__ unsigned short As[128*32];
    __shared__ unsigned short Bs[128*32];
    int t  = threadIdx.x;
    int m0 = blockIdx.x * 128;
    int n0 = blockIdx.y * 128;
    int w  = t >> 6, l = t & 63;
    int wm = w & 1, wn = w >> 1;
    int lr = l & 15;
    int lq = l >> 4;

    int s0 = w*2, s1 = w*2 + 1;
    int srow = l >> 2;
    int sko  = (l & 3) * 8;
    int rowA0 = s0*16 + srow, rowA1 = s1*16 + srow;
    unsigned short* ldsA0 = As + s0*512 + l*8;
    unsigned short* ldsA1 = As + s1*512 + l*8;
    unsigned short* ldsB0 = Bs + s0*512 + l*8;
    unsigned short* ldsB1 = Bs + s1*512 + l*8;

    f32x4 acc[4][4];
    #pragma unroll
    for (int mi = 0; mi < 4; ++mi)
        #pragma unroll
        for (int ni = 0; ni < 4; ++ni)
            #pragma unroll
            for (int r = 0; r < 4; ++r) acc[mi][ni][r] = 0.f;

    for (int k0 = 0; k0 < K; k0 += 32) {
        glds16(A  + (size_t)(m0 + rowA0)*K + k0 + sko, ldsA0);
        glds16(A  + (size_t)(m0 + rowA1)*K + k0 + sko, ldsA1);
        glds16(BT + (size_t)(n0 + rowA0)*K + k0 + sko, ldsB0);
        glds16(BT + (size_t)(n0 + rowA1)*K + k0 + sko, ldsB1);
        __syncthreads();
        bf16x8 af[4], bf[4];
        #pragma unroll
        for (int mi = 0; mi < 4; ++mi)
            af[mi] = *(const bf16x8*)(As + (wm*64 + mi*16 + lr)*32 + lq*8);
        #pragma unroll
        for (int ni = 0; ni < 4; ++ni)
            bf[ni] = *(const bf16x8*)(Bs + (wn*64 + ni*16 + lr)*32 + lq*8);
        #pragma unroll
        for (int mi = 0; mi < 4; ++mi)
            #pragma unroll
            for (int ni = 0; ni < 4; ++ni)
                acc[mi][ni] = __builtin_amdgcn_mfma_f32_16x16x32_bf16(af[mi], bf[ni], acc[mi][ni], 0, 0, 0);
        __syncthreads();
    }

    #pragma unroll
    for (int mi = 0; mi < 4; ++mi) {
        #pragma unroll
        for (int ni = 0; ni < 4; ++ni) {
            int gc = n0 + wn*64 + ni*16 + lr;
            int gr = m0 + wm*64 + mi*16 + lq*4;
            float bval = bias ? bias[gc] : 0.f;
            #pragma unroll
            for (int r = 0; r < 4; ++r) {
                float v = acc[mi][ni][r] + bval;
                if (RELU) v = relu_(v);
                if (OUT_BF16) ((unsigned short*)Cv)[(size_t)(gr + r)*N + gc] = f2b(v);
                else          ((float*)Cv)[(size_t)(gr + r)*N + gc] = v;
            }
        }
    }
}

// -------- h1 via MFMA: h1 = relu(geo@W1c + U[b,j] + V[b,i] + b1) -> bf16 ----------
__global__ __launch_bounds__(256) void k_h1m(
    const unsigned short* __restrict__ A,
    const unsigned short* __restrict__ BT,
    const float* __restrict__ b1,
    const float* __restrict__ U, const float* __restrict__ V,
    unsigned short* __restrict__ h1c, int pofs)
{
    __shared__ unsigned short As[128*32];
    __shared__ unsigned short Bs[128*32];
    const int K = GEO;   // 64
    int t  = threadIdx.x;
    int m0 = blockIdx.x * 128;
    int n0 = blockIdx.y * 128;
    int w  = t >> 6, l = t & 63;
    int wm = w & 1, wn = w >> 1;
    int lr = l & 15;
    int lq = l >> 4;

    int s0 = w*2, s1 = w*2 + 1;
    int srow = l >> 2;
    int sko  = (l & 3) * 8;
    int rowA0 = s0*16 + srow, rowA1 = s1*16 + srow;
    unsigned short* ldsA0 = As + s0*512 + l*8;
    unsigned short* ldsA1 = As + s1*512 + l*8;
    unsigned short* ldsB0 = Bs + s0*512 + l*8;
    unsigned short* ldsB1 = Bs + s1*512 + l*8;

    f32x4 acc[4][4];
    #pragma unroll
    for (int mi = 0; mi < 4; ++mi)
        #pragma unroll
        for (int ni = 0; ni < 4; ++ni)
            #pragma unroll
            for (int r = 0; r < 4; ++r) acc[mi][ni][r] = 0.f;

    for (int k0 = 0; k0 < K; k0 += 32) {
        glds16(A  + (size_t)(m0 + rowA0)*K + k0 + sko, ldsA0);
        glds16(A  + (size_t)(m0 + rowA1)*K + k0 + sko, ldsA1);
        glds16(BT + (size_t)(n0 + rowA0)*K + k0 + sko, ldsB0);
        glds16(BT + (size_t)(n0 + rowA1)*K + k0 + sko, ldsB1);
        __syncthreads();
        bf16x8 af[4], bf[4];
        #pragma unroll
        for (int mi = 0; mi < 4; ++mi)
            af[mi] = *(const bf16x8*)(As + (wm*64 + mi*16 + lr)*32 + lq*8);
        #pragma unroll
        for (int ni = 0; ni < 4; ++ni)
            bf[ni] = *(const bf16x8*)(Bs + (wn*64 + ni*16 + lr)*32 + lq*8);
        #pragma unroll
        for (int mi = 0; mi < 4; ++mi)
            #pragma unroll
            for (int ni = 0; ni < 4; ++ni)
                acc[mi][ni] = __builtin_amdgcn_mfma_f32_16x16x32_bf16(af[mi], bf[ni], acc[mi][ni], 0, 0, 0);
        __syncthreads();
    }

    // epilogue: rows of this block are j = 0..127 (p0 multiple of 128), i constant
    int p0 = pofs + m0;
    int bi = p0 >> 7;            // b*NP + i
    int b  = bi >> 7;
    const float* Ubase = U + (size_t)b*NP*D;
    const float* Vrow  = V + (size_t)bi*D;
    #pragma unroll
    for (int ni = 0; ni < 4; ++ni) {
        int gc = n0 + wn*64 + ni*16 + lr;
        float add = Vrow[gc] + b1[gc];
        #pragma unroll
        for (int mi = 0; mi < 4; ++mi) {
            int row = wm*64 + mi*16 + lq*4;
            #pragma unroll
            for (int r = 0; r < 4; ++r) {
                float u = Ubase[(size_t)(row + r)*D + gc];
                float val = acc[mi][ni][r] + u + add;
                h1c[(size_t)(m0 + row + r)*D + gc] = f2b(relu_(val));
            }
        }
    }
}

// ------- fused fet GEMM + top-18 + sum/8 (512 threads) --------------------------
// GEMM by t<256 (m97 structure); topk: 4 threads/channel x 32 j, 2-level merge.
// LDS 33280 B total: As/Bs (k-loop) -> tile -> L1 (0..18432) + L2 (18432..27648).
#define TLDS 130
__global__ __launch_bounds__(512) void k_mgemm_topk(
    const unsigned short* __restrict__ A,
    const unsigned short* __restrict__ BT,
    const float* __restrict__ bias,
    float* __restrict__ red_out,
    int N, int K)
{
    __shared__ unsigned char smem[128*TLDS*2];               // 33280 B
    unsigned short* As   = (unsigned short*)smem;            // k-loop phase
    unsigned short* Bs   = As + 128*32;
    unsigned short* tile = (unsigned short*)smem;            // tile phase (alias)
    unsigned short* L1   = (unsigned short*)smem;            // 512*18 = 18432 B
    unsigned short* L2   = (unsigned short*)(smem + 512*TOPKN*2);  // 256*18 = 9216 B

    int t  = threadIdx.x;
    int m0 = blockIdx.x * 128;
    int n0 = blockIdx.y * 128;
    int w  = t >> 6, l = t & 63;
    int wm = w & 1, wn = w >> 1;
    int lr = l & 15;
    int lq = l >> 4;

    int s0 = w*2, s1 = w*2 + 1;
    int sko  = (l & 3) * 8;
    int srow = l >> 2;
    int rowA0 = s0*16 + srow, rowA1 = s1*16 + srow;
    unsigned short* ldsA0 = As + s0*512 + l*8;
    unsigned short* ldsA1 = As + s1*512 + l*8;
    unsigned short* ldsB0 = Bs + s0*512 + l*8;
    unsigned short* ldsB1 = Bs + s1*512 + l*8;

    f32x4 acc[4][4];
    #pragma unroll
    for (int mi = 0; mi < 4; ++mi)
        #pragma unroll
        for (int ni = 0; ni < 4; ++ni)
            #pragma unroll
            for (int r = 0; r < 4; ++r) acc[mi][ni][r] = 0.f;

    for (int k0 = 0; k0 < K; k0 += 32) {
        if (t < 256) {
            glds16(A  + (size_t)(m0 + rowA0)*K + k0 + sko, ldsA0);
            glds16(A  + (size_t)(m0 + rowA1)*K + k0 + sko, ldsA1);
            glds16(BT + (size_t)(n0 + rowA0)*K + k0 + sko, ldsB0);
            glds16(BT + (size_t)(n0 + rowA1)*K + k0 + sko, ldsB1);
        }
        __syncthreads();
        if (t < 256) {
            bf16x8 af[4], bf[4];
            #pragma unroll
            for (int mi = 0; mi < 4; ++mi)
                af[mi] = *(const bf16x8*)(As + (wm*64 + mi*16 + lr)*32 + lq*8);
            #pragma unroll
            for (int ni = 0; ni < 4; ++ni)
                bf[ni] = *(const bf16x8*)(Bs + (wn*64 + ni*16 + lr)*32 + lq*8);
            #pragma unroll
            for (int mi = 0; mi < 4; ++mi)
                #pragma unroll
                for (int ni = 0; ni < 4; ++ni)
                    acc[mi][ni] = __builtin_amdgcn_mfma_f32_16x16x32_bf16(af[mi], bf[ni], acc[mi][ni], 0, 0, 0);
        }
        __syncthreads();
    }

    // phase 2: fet tile (bias added, bf16) -> LDS. row = j, col = channel.
    if (t < 256) {
        #pragma unroll
        for (int mi = 0; mi < 4; ++mi) {
            #pragma unroll
            for (int ni = 0; ni < 4; ++ni) {
                int col = wn*64 + ni*16 + lr;
                int row = wm*64 + mi*16 + lq*4;
                float bval = bias[n0 + col];
                #pragma unroll
                for (int r = 0; r < 4; ++r)
                    tile[(row + r)*TLDS + col] = f2b(acc[mi][ni][r] + bval);
            }
        }
    }
    __syncthreads();

    // phase 3: 4 threads/channel, top-18 over 32 j each
    int c = t & 127, q = t >> 7;
    float sm[TOPKN];
    #pragma unroll
    for (int x = 0; x < TOPKN; ++x) sm[x] = -INFINITY;
    int jbase = q*32;
    for (int j = 0; j < 32; ++j) {
        float v = b2f(tile[(jbase + j)*TLDS + c]);
        #pragma unroll
        for (int x = 0; x < TOPKN; ++x) {
            float mx = fmaxf(sm[x], v);
            v = fminf(sm[x], v);
            sm[x] = mx;
        }
    }
    __syncthreads();   // tile dead -> alias as L1
    {
        unsigned short* my = L1 + (size_t)t*TOPKN;
        #pragma unroll
        for (int x = 0; x < TOPKN; ++x) my[x] = f2b(sm[x]);
    }
    __syncthreads();

    // phase 4: t<256 merges L1 pairs (q=2h,2h+1) -> L2
    if (t < 256) {
        int h = t >> 7;
        const unsigned short* la = L1 + (size_t)((2*h)*128 + c)*TOPKN;
        const unsigned short* lb = L1 + (size_t)((2*h+1)*128 + c)*TOPKN;
        unsigned short* dst = L2 + (size_t)(h*128 + c)*TOPKN;
        int ia = 0, ib = 0;
        float av = b2f(la[0]), bv = b2f(lb[0]);
        #pragma unroll
        for (int x = 0; x < TOPKN; ++x) {
            bool ta = (av >= bv);
            dst[x] = f2b(ta ? av : bv);
            if (ta) { ++ia; av = (ia < TOPKN) ? b2f(la[ia]) : -INFINITY; }
            else    { ++ib; bv = (ib < TOPKN) ? b2f(lb[ib]) : -INFINITY; }
        }
    }
    __syncthreads();

    // phase 5: t<128 merges L2 pair, sum top-18
    if (t < 128) {
        const unsigned short* la = L2 + (size_t)t*TOPKN;
        const unsigned short* lb = L2 + (size_t)(128 + t)*TOPKN;
        int ia = 0, ib = 0;
        float av = b2f(la[0]), bv = b2f(lb[0]);
        float s = 0.f;
        #pragma unroll
        for (int x = 0; x < TOPKN; ++x) {
            bool ta = (av >= bv);
            s += ta ? av : bv;
            if (ta) { ++ia; av = (ia < TOPKN) ? b2f(la[ia]) : -INFINITY; }
            else    { ++ib; bv = (ib < TOPKN) ? b2f(lb[ib]) : -INFINITY; }
        }
        red_out[(size_t)blockIdx.x*N + n0 + t] = s * 0.125f;
    }
}

// ---------------- final heads -> sigmoid, f32 out ----------------
__global__ __launch_bounds__(256) void k_final(const float* __restrict__ x,
    const float* __restrict__ subject, const float* __restrict__ obj,
    const float* __restrict__ cs_w, const float* __restrict__ cs_b,
    const float* __restrict__ cso_w, const float* __restrict__ cso_b,
    float* __restrict__ out)
{
    int bi = blockIdx.x;
    int b  = bi >> 7;
    const float* xr = x + (size_t)bi*D;
    const float* sb = subject + (size_t)b*D;
    const float* ob = obj + (size_t)b*D;
    int tid = threadIdx.x;
    float a0 = 0.f, a1 = 0.f;
    for (int k = tid; k < D; k += 256) {
        float xv = xr[k];
        a0 = fmaf(xv, cs_w[k], a0);
        a0 = fmaf(sb[k], cs_w[D+k], a0);
        a1 = fmaf(xv, cso_w[k], a1);
        a1 = fmaf(ob[k], cso_w[D+k], a1);
    }
    __shared__ float r0[256], r1[256];
    r0[tid] = a0; r1[tid] = a1;
    __syncthreads();
    for (int s2 = 128; s2 > 0; s2 >>= 1) {
        if (tid < s2) { r0[tid] += r0[tid+s2]; r1[tid] += r1[tid+s2]; }
        __syncthreads();
    }
    if (tid == 0) {
        out[bi*2+0] = 1.f/(1.f + expf(-(r0[0] + cs_b[0])));
        out[bi*2+1] = 1.f/(1.f + expf(-(r1[0] + cso_b[0])));
    }
}

extern "C" void kernel_launch(void* const* d_in, const int* in_sizes, int n_in,
                              void* d_out, int out_size, void* d_ws, size_t ws_size,
                              hipStream_t stream)
{
    const float* feats   = (const float*)d_in[0];
    const float* subject = (const float*)d_in[1];
    const float* obj     = (const float*)d_in[2];
    const float* prop    = (const float*)d_in[3];
    const float* gp_w1 = (const float*)d_in[4];  const float* gp_b1 = (const float*)d_in[5];
    const float* gp_w2 = (const float*)d_in[6];  const float* gp_b2 = (const float*)d_in[7];
    const float* gp_w3 = (const float*)d_in[8];  const float* gp_b3 = (const float*)d_in[9];
    const float* pm_w1 = (const float*)d_in[10]; const float* pm_b1 = (const float*)d_in[11];
    const float* pm_w2 = (const float*)d_in[12]; const float* pm_b2 = (const float*)d_in[13];
    const float* pm_w3 = (const float*)d_in[14]; const float* pm_b3 = (const float*)d_in[15];
    const float* ag_w1 = (const float*)d_in[16]; const float* ag_b1 = (const float*)d_in[17];
    const float* ag_w2 = (const float*)d_in[18]; const float* ag_b2 = (const float*)d_in[19];
    const float* ag_w3 = (const float*)d_in[20]; const float* ag_b3 = (const float*)d_in[21];
    const float* cs_w  = (const float*)d_in[22]; const float* cs_b  = (const float*)d_in[23];
    const float* cso_w = (const float*)d_in[24]; const float* cso_b = (const float*)d_in[25];
    float* out = (float*)d_out;

    const int M = BS*NP;          // 256
    const int MN = M*D;           // 262144

    // ---- workspace layout (bytes). Persist ~21 MB; Cp aliases the chunk region ----
    char* wsb = (char*)d_ws;
    size_t off = 0;
    auto alloc = [&](size_t bytes) { char* p = wsb + off; off += (bytes + 255) & ~255ull; return p; };
    float* Ub  = (float*)alloc((size_t)MN*4);
    float* Vb  = (float*)alloc((size_t)MN*4);
    float* red = (float*)alloc((size_t)MN*4);
    float* xf  = (float*)alloc((size_t)MN*4);
    unsigned short* xh1b = (unsigned short*)alloc((size_t)MN*2);
    unsigned short* xh2b = (unsigned short*)alloc((size_t)MN*2);
    unsigned short* w1aT = (unsigned short*)alloc((size_t)D*D*2);
    unsigned short* w1bT = (unsigned short*)alloc((size_t)D*D*2);
    unsigned short* w1cT = (unsigned short*)alloc((size_t)D*GEO*2);
    unsigned short* w2T  = (unsigned short*)alloc((size_t)D*D*2);
    unsigned short* w3T  = (unsigned short*)alloc((size_t)D*D*2);
    unsigned short* agw1T= (unsigned short*)alloc((size_t)2*D*D*2);
    unsigned short* agw2T= (unsigned short*)alloc((size_t)D*D*2);
    unsigned short* agw3T= (unsigned short*)alloc((size_t)D*D*2);
    size_t persist = off;

    // shared region: Cp (split-K partials, phases 1&3) ALIASES chunk bufs (phase 2)
    size_t cp_bytes = (size_t)8*MN*4;                       // 8.4 MB
    size_t chunk_unit = (size_t)NP*(GEO*2 + D*2 + D*2);     // 540.7 KB per CH-row
    int CH = M;  // try the whole problem in one chunk
    while (CH > 1) {
        size_t region = (size_t)CH*chunk_unit;
        if (region < cp_bytes) region = cp_bytes;
        if (persist + region + 4096 <= ws_size) break;
        CH >>= 1;
    }
    float*          Cp    = (float*)(wsb + persist);
    unsigned short* geoPc = (unsigned short*)(wsb + persist);
    unsigned short* h1c   = geoPc + (size_t)CH*NP*GEO;
    unsigned short* h2c   = h1c   + (size_t)CH*NP*D;

    // 0) all weight transposes + bf16 in one dispatch (incl. W1c geo slice)
    WT8 d;
    d.src[0]=pm_w1;                d.dst[0]=w1aT;  d.kt[0]=16;
    d.src[1]=pm_w1+(size_t)D*D;    d.dst[1]=w1bT;  d.kt[1]=16;
    d.src[2]=pm_w1+(size_t)2*D*D;  d.dst[2]=w1cT;  d.kt[2]=1;
    d.src[3]=pm_w2;                d.dst[3]=w2T;   d.kt[3]=16;
    d.src[4]=pm_w3;                d.dst[4]=w3T;   d.kt[4]=16;
    d.src[5]=ag_w1;                d.dst[5]=agw1T; d.kt[5]=32;
    d.src[6]=ag_w2;                d.dst[6]=agw2T; d.kt[6]=16;
    d.src[7]=ag_w3;                d.dst[7]=agw3T; d.kt[7]=16;
    d.pre[0]=0;
    for (int e = 0; e < 8; ++e) d.pre[e+1] = d.pre[e] + d.kt[e]*16;
    k_wTall<<<d.pre[8], 256, 0, stream>>>(d);

    // 1) U,V = feats @ {w1a, w1b}: split-K MFMA (KZ=4, 2 mats) + reduce
    k_skmm<true><<<dim3(M/16, D/128, 8), 256, 0, stream>>>(
        feats, nullptr, D, 0, w1aT, w1bT, Cp, 4, 256, D);
    k_red<false,false><<<dim3(MN/1024, 1, 2), 256, 0, stream>>>(
        Cp, 4, nullptr, Ub, Vb, MN, D);

    // 2) chunked over (b,i) rows: geo(bf16) -> h1(MFMA) -> h2 -> fused fet+topk
    int nchunks = M/CH;
    for (int cchunk = 0; cchunk < nchunks; ++cchunk) {
        int bi0  = cchunk * CH;
        int pofs = bi0 * NP;
        k_geo<<<CH*NP/4, 256, 0, stream>>>(prop, gp_w1, gp_b1, gp_w2, gp_b2, gp_w3, gp_b3, geoPc, pofs);
        dim3 gBig(CH*NP/128, D/128);
        k_h1m<<<gBig, 256, 0, stream>>>(geoPc, w1cT, pm_b1, Ub, Vb, h1c, pofs);
        k_mgemm<true,true><<<gBig, 256, 0, stream>>>(h1c, w2T, pm_b2, h2c, CH*NP, D, D);
        k_mgemm_topk<<<dim3(CH, D/128), 512, 0, stream>>>(h2c, w3T, pm_b3,
                                                          red + (size_t)bi0*D, D, D);
    }

    // 3) aggregate MLP via split-K MFMA + fused reduce/activation
    k_skmm<true><<<dim3(M/16, D/128, 8), 256, 0, stream>>>(
        feats, red, D, D, agw1T, nullptr, Cp, 8, 256, D);
    k_red<true,true><<<dim3(MN/1024, 1, 1), 256, 0, stream>>>(
        Cp, 8, ag_b1, xh1b, nullptr, MN, D);
    k_skmm<false><<<dim3(M/16, D/128, 4), 256, 0, stream>>>(
        xh1b, nullptr, D, 0, agw2T, nullptr, Cp, 4, 256, D);
    k_red<true,true><<<dim3(MN/1024, 1, 1), 256, 0, stream>>>(
        Cp, 4, ag_b2, xh2b, nullptr, MN, D);
    k_skmm<false><<<dim3(M/16, D/128, 4), 256, 0, stream>>>(
        xh2b, nullptr, D, 0, agw3T, nullptr, Cp, 4, 256, D);
    k_red<false,false><<<dim3(MN/1024, 1, 1), 256, 0, stream>>>(
        Cp, 4, ag_b3, xf, nullptr, MN, D);

    // 4) sigmoid heads
    k_final<<<M, 256, 0, stream>>>(xf, subject, obj, cs_w, cs_b, cso_w, cso_b, out);
}